// Round 6
// baseline (858.390 us; speedup 1.0000x reference)
//
#include <hip/hip_runtime.h>
#include <hip/hip_bf16.h>
#include <cmath>

#define TK 12
#define NROW 12288
#define NEG_BIG (-3.0e38f)
#define MFMA16(a,b,c) __builtin_amdgcn_mfma_f32_16x16x32_f16(a,b,c,0,0,0)

// 16 column chunks of 768 cols = 48 tiles of 16 cols; 24 32-col groups/chunk
#define NCH 16
#define CTILES 48
#define NGRP 24

typedef _Float16 f16x8 __attribute__((ext_vector_type(8)));
typedef float    f32x4 __attribute__((ext_vector_type(4)));

typedef __attribute__((address_space(1))) const void gvoid_t;
typedef __attribute__((address_space(3))) void lvoid_t;
__device__ __forceinline__ void gload_lds16(const void* g, void* l) {
    __builtin_amdgcn_global_load_lds((gvoid_t*)g, (lvoid_t*)l, 16, 0, 0);
}

// ---------------------------------------------------------------------------
// wpack: W [K][N] f32 -> A-operand fragments of W^T, hi/lo f16.
// P[cg][s][l][j] = W[s*32 + 8*(l>>4) + j][cg*16 + (l&15)], linear idx = tid*8.
// ---------------------------------------------------------------------------
__global__ __launch_bounds__(256) void wpack(
    const float* __restrict__ W, _Float16* __restrict__ hi,
    _Float16* __restrict__ lo, int N, int nkt)
{
    const int tid = blockIdx.x * 256 + threadIdx.x;
    const int l = tid & 63;
    const int s = (tid >> 6) % nkt;
    const int cg = tid / (nkt * 64);
    const int krow = s * 32 + 8 * (l >> 4);
    const int col = cg * 16 + (l & 15);
    f16x8 H, L;
    #pragma unroll
    for (int j = 0; j < 8; ++j) {
        float w = W[(size_t)(krow + j) * N + col];
        _Float16 h = (_Float16)w;
        H[j] = h;
        L[j] = (_Float16)(w - (float)h);
    }
    *(f16x8*)(hi + (size_t)tid * 8) = H;
    *(f16x8*)(lo + (size_t)tid * 8) = L;
}

// ---------------------------------------------------------------------------
// gemm_mfma: C = act( A @ W + bias ), 3-term f16-split MFMA (used for K1).
// Grid (2, 192); block = 64 rows x 128 cols; wave owns 2 colgroups.
// ---------------------------------------------------------------------------
template<bool RELU>
__global__ __launch_bounds__(256) void gemm_mfma(
    const float* __restrict__ A1,
    const _Float16* __restrict__ Wh, const _Float16* __restrict__ Wl,
    const float* __restrict__ bias, float* __restrict__ C, int K)
{
    __shared__ _Float16 aH[4*64*8], aL[4*64*8];
    __shared__ _Float16 wH[8*64*8], wL[8*64*8];
    const int tid = threadIdx.x, lane = tid & 63, wave = tid >> 6;
    const int rb = blockIdx.y * 64;
    const int cbg = blockIdx.x * 8;
    const int nkt = K >> 5;

    const int arow = rb + wave * 16 + (lane & 15);
    const int acol0 = 8 * (lane >> 4);
    const float* a1p = A1 + (size_t)arow * K + acol0;

    f32x4 acc[4][2];
    #pragma unroll
    for (int rg = 0; rg < 4; ++rg)
        #pragma unroll
        for (int c = 0; c < 2; ++c) acc[rg][c] = (f32x4){0.f,0.f,0.f,0.f};

    for (int kt = 0; kt < nkt; ++kt) {
        __syncthreads();
        {
            float v[8];
            *(float4*)v       = *(const float4*)(a1p + kt*32);
            *(float4*)(v + 4) = *(const float4*)(a1p + kt*32 + 4);
            f16x8 H, L;
            #pragma unroll
            for (int j = 0; j < 8; ++j) {
                _Float16 h = (_Float16)v[j];
                H[j] = h;
                L[j] = (_Float16)(v[j] - (float)h);
            }
            *(f16x8*)&aH[tid*8] = H;
            *(f16x8*)&aL[tid*8] = L;
        }
        #pragma unroll
        for (int i = 0; i < 2; ++i) {
            const int slot = tid + i*256;
            const int c = slot >> 6, l2 = slot & 63;
            const size_t goff = ((size_t)(cbg + c) * nkt + kt) * 512 + l2*8;
            *(f16x8*)&wH[slot*8] = *(const f16x8*)(Wh + goff);
            *(f16x8*)&wL[slot*8] = *(const f16x8*)(Wl + goff);
        }
        __syncthreads();
        f16x8 wh0 = *(const f16x8*)&wH[((wave*2+0)*64 + lane)*8];
        f16x8 wl0 = *(const f16x8*)&wL[((wave*2+0)*64 + lane)*8];
        f16x8 wh1 = *(const f16x8*)&wH[((wave*2+1)*64 + lane)*8];
        f16x8 wl1 = *(const f16x8*)&wL[((wave*2+1)*64 + lane)*8];
        #pragma unroll
        for (int rg = 0; rg < 4; ++rg) {
            f16x8 ah = *(const f16x8*)&aH[(rg*64 + lane)*8];
            f16x8 al = *(const f16x8*)&aL[(rg*64 + lane)*8];
            acc[rg][0] = MFMA16(wh0, ah, acc[rg][0]);
            acc[rg][0] = MFMA16(wl0, ah, acc[rg][0]);
            acc[rg][0] = MFMA16(wh0, al, acc[rg][0]);
            acc[rg][1] = MFMA16(wh1, ah, acc[rg][1]);
            acc[rg][1] = MFMA16(wl1, ah, acc[rg][1]);
            acc[rg][1] = MFMA16(wh1, al, acc[rg][1]);
        }
    }
    #pragma unroll
    for (int rg = 0; rg < 4; ++rg) {
        const int row = rb + rg*16 + (lane & 15);
        #pragma unroll
        for (int c = 0; c < 2; ++c) {
            const int col = (cbg + wave*2 + c)*16 + 4*(lane >> 4);
            float4 b4 = *(const float4*)(bias + col);
            float4 o;
            o.x = acc[rg][c][0] + b4.x;
            o.y = acc[rg][c][1] + b4.y;
            o.z = acc[rg][c][2] + b4.z;
            o.w = acc[rg][c][3] + b4.w;
            if (RELU) {
                o.x = fmaxf(o.x, 0.f); o.y = fmaxf(o.y, 0.f);
                o.z = fmaxf(o.z, 0.f); o.w = fmaxf(o.w, 0.f);
            }
            *(float4*)(C + (size_t)row*256 + col) = o;
        }
    }
}

// ---------------------------------------------------------------------------
// gemm_dual: K=N=256 fused pair.
//  DMODE 0: C1 = A1@W1 + b1 ; C2 = A1@W2 + b2          (A staged once)
//  DMODE 1: C1 = relu((A1+A2)@W1+b1) + relu((A1*A2)@W2+b2)
// ---------------------------------------------------------------------------
template<int DMODE>
__global__ __launch_bounds__(256) void gemm_dual(
    const float* __restrict__ A1, const float* __restrict__ A2,
    const _Float16* __restrict__ W1h, const _Float16* __restrict__ W1l,
    const _Float16* __restrict__ W2h, const _Float16* __restrict__ W2l,
    const float* __restrict__ bias1, const float* __restrict__ bias2,
    float* __restrict__ C1, float* __restrict__ C2)
{
    __shared__ _Float16 aH[2][2048], aL[2][2048];
    __shared__ _Float16 wH[2][4096], wL[2][4096];
    const int tid = threadIdx.x, lane = tid & 63, wave = tid >> 6;
    const int rb = blockIdx.y * 64;
    const int cbg = blockIdx.x * 8;

    const int arow = rb + wave * 16 + (lane & 15);
    const int acol0 = 8 * (lane >> 4);
    const float* a1p = A1 + (size_t)arow * 256 + acol0;
    const float* a2p = (DMODE == 1) ? (A2 + (size_t)arow * 256 + acol0) : nullptr;

    f32x4 acc1[4][2], acc2[4][2];
    #pragma unroll
    for (int rg = 0; rg < 4; ++rg)
        #pragma unroll
        for (int c = 0; c < 2; ++c) {
            acc1[rg][c] = (f32x4){0.f,0.f,0.f,0.f};
            acc2[rg][c] = (f32x4){0.f,0.f,0.f,0.f};
        }

    for (int kt = 0; kt < 8; ++kt) {
        __syncthreads();
        {
            float v[8];
            *(float4*)v       = *(const float4*)(a1p + kt*32);
            *(float4*)(v + 4) = *(const float4*)(a1p + kt*32 + 4);
            if (DMODE == 0) {
                f16x8 H, L;
                #pragma unroll
                for (int j = 0; j < 8; ++j) {
                    _Float16 h = (_Float16)v[j];
                    H[j] = h;
                    L[j] = (_Float16)(v[j] - (float)h);
                }
                *(f16x8*)&aH[0][tid*8] = H;
                *(f16x8*)&aL[0][tid*8] = L;
            } else {
                float b[8];
                *(float4*)b       = *(const float4*)(a2p + kt*32);
                *(float4*)(b + 4) = *(const float4*)(a2p + kt*32 + 4);
                f16x8 Hs, Ls, Hm, Lm;
                #pragma unroll
                for (int j = 0; j < 8; ++j) {
                    float s = v[j] + b[j];
                    float m = v[j] * b[j];
                    _Float16 hs = (_Float16)s;
                    _Float16 hm = (_Float16)m;
                    Hs[j] = hs; Ls[j] = (_Float16)(s - (float)hs);
                    Hm[j] = hm; Lm[j] = (_Float16)(m - (float)hm);
                }
                *(f16x8*)&aH[0][tid*8] = Hs;
                *(f16x8*)&aL[0][tid*8] = Ls;
                *(f16x8*)&aH[1][tid*8] = Hm;
                *(f16x8*)&aL[1][tid*8] = Lm;
            }
        }
        #pragma unroll
        for (int i = 0; i < 2; ++i) {
            const int slot = tid + i*256;
            const int c = slot >> 6, l2 = slot & 63;
            const size_t goff = ((size_t)(cbg + c) * 8 + kt) * 512 + l2*8;
            *(f16x8*)&wH[0][slot*8] = *(const f16x8*)(W1h + goff);
            *(f16x8*)&wL[0][slot*8] = *(const f16x8*)(W1l + goff);
            *(f16x8*)&wH[1][slot*8] = *(const f16x8*)(W2h + goff);
            *(f16x8*)&wL[1][slot*8] = *(const f16x8*)(W2l + goff);
        }
        __syncthreads();
        f16x8 w1h0 = *(const f16x8*)&wH[0][((wave*2+0)*64 + lane)*8];
        f16x8 w1l0 = *(const f16x8*)&wL[0][((wave*2+0)*64 + lane)*8];
        f16x8 w1h1 = *(const f16x8*)&wH[0][((wave*2+1)*64 + lane)*8];
        f16x8 w1l1 = *(const f16x8*)&wL[0][((wave*2+1)*64 + lane)*8];
        f16x8 w2h0 = *(const f16x8*)&wH[1][((wave*2+0)*64 + lane)*8];
        f16x8 w2l0 = *(const f16x8*)&wL[1][((wave*2+0)*64 + lane)*8];
        f16x8 w2h1 = *(const f16x8*)&wH[1][((wave*2+1)*64 + lane)*8];
        f16x8 w2l1 = *(const f16x8*)&wL[1][((wave*2+1)*64 + lane)*8];
        #pragma unroll
        for (int rg = 0; rg < 4; ++rg) {
            f16x8 ah0 = *(const f16x8*)&aH[0][(rg*64 + lane)*8];
            f16x8 al0 = *(const f16x8*)&aL[0][(rg*64 + lane)*8];
            acc1[rg][0] = MFMA16(w1h0, ah0, acc1[rg][0]);
            acc1[rg][0] = MFMA16(w1l0, ah0, acc1[rg][0]);
            acc1[rg][0] = MFMA16(w1h0, al0, acc1[rg][0]);
            acc1[rg][1] = MFMA16(w1h1, ah0, acc1[rg][1]);
            acc1[rg][1] = MFMA16(w1l1, ah0, acc1[rg][1]);
            acc1[rg][1] = MFMA16(w1h1, al0, acc1[rg][1]);
            f16x8 ah1 = (DMODE == 1) ? *(const f16x8*)&aH[1][(rg*64 + lane)*8] : ah0;
            f16x8 al1 = (DMODE == 1) ? *(const f16x8*)&aL[1][(rg*64 + lane)*8] : al0;
            acc2[rg][0] = MFMA16(w2h0, ah1, acc2[rg][0]);
            acc2[rg][0] = MFMA16(w2l0, ah1, acc2[rg][0]);
            acc2[rg][0] = MFMA16(w2h0, al1, acc2[rg][0]);
            acc2[rg][1] = MFMA16(w2h1, ah1, acc2[rg][1]);
            acc2[rg][1] = MFMA16(w2l1, ah1, acc2[rg][1]);
            acc2[rg][1] = MFMA16(w2h1, al1, acc2[rg][1]);
        }
    }
    #pragma unroll
    for (int rg = 0; rg < 4; ++rg) {
        const int row = rb + rg*16 + (lane & 15);
        #pragma unroll
        for (int c = 0; c < 2; ++c) {
            const int col = (cbg + wave*2 + c)*16 + 4*(lane >> 4);
            float4 b14 = *(const float4*)(bias1 + col);
            float4 b24 = *(const float4*)(bias2 + col);
            if (DMODE == 0) {
                float4 o1, o2;
                o1.x = acc1[rg][c][0] + b14.x; o1.y = acc1[rg][c][1] + b14.y;
                o1.z = acc1[rg][c][2] + b14.z; o1.w = acc1[rg][c][3] + b14.w;
                o2.x = acc2[rg][c][0] + b24.x; o2.y = acc2[rg][c][1] + b24.y;
                o2.z = acc2[rg][c][2] + b24.z; o2.w = acc2[rg][c][3] + b24.w;
                *(float4*)(C1 + (size_t)row*256 + col) = o1;
                *(float4*)(C2 + (size_t)row*256 + col) = o2;
            } else {
                float4 o;
                o.x = fmaxf(acc1[rg][c][0] + b14.x, 0.f) + fmaxf(acc2[rg][c][0] + b24.x, 0.f);
                o.y = fmaxf(acc1[rg][c][1] + b14.y, 0.f) + fmaxf(acc2[rg][c][1] + b24.y, 0.f);
                o.z = fmaxf(acc1[rg][c][2] + b14.z, 0.f) + fmaxf(acc2[rg][c][2] + b24.z, 0.f);
                o.w = fmaxf(acc1[rg][c][3] + b14.w, 0.f) + fmaxf(acc2[rg][c][3] + b24.w, 0.f);
                *(float4*)(C1 + (size_t)row*256 + col) = o;
            }
        }
    }
}

// ---------------------------------------------------------------------------
// pack_hi: X f32 [12288][256] (scaled) -> hi f16 in MFMA fragment order.
// ---------------------------------------------------------------------------
__global__ __launch_bounds__(256) void pack_hi(
    const float* __restrict__ X, _Float16* __restrict__ hi, float scale)
{
    const int tid = blockIdx.x * 256 + threadIdx.x;
    const int g = tid >> 9;
    const int rem = tid & 511;
    const int s = rem >> 6, l = rem & 63;
    const float* src = X + (size_t)(g*16 + (l & 15))*256 + s*32 + 8*(l >> 4);
    float4 v0 = *(const float4*)src;
    float4 v1 = *(const float4*)(src + 4);
    float vv[8] = {v0.x, v0.y, v0.z, v0.w, v1.x, v1.y, v1.z, v1.w};
    f16x8 H;
    #pragma unroll
    for (int j = 0; j < 8; ++j) H[j] = (_Float16)(vv[j] * scale);
    *(f16x8*)(hi + (size_t)tid * 8) = H;
}

// ---------------------------------------------------------------------------
// S1: per-(row, 32-col-group) maxima, 1-term f16. Grid 16 chunks x 48 row-
// blocks = 768 blocks (3/CU). Block = 4 waves x 64 rows = 256 rows x 768-col
// chunk. Triple-buffered global_load_lds + counted vmcnt.
// ---------------------------------------------------------------------------
__global__ __launch_bounds__(256, 4) void s1_gmax(
    const _Float16* __restrict__ ehh, const _Float16* __restrict__ eth,
    unsigned short* __restrict__ gmax16)
{
    __shared__ _Float16 abuf[3][4096];          // 3 x 8KB tiles
    __shared__ unsigned short gml[NGRP * 256];  // 12KB
    const int tid = threadIdx.x, lane = tid & 63, wave = tid >> 6;
    const int chunk = blockIdx.x & (NCH-1);
    const int rblk = blockIdx.x >> 4;           // 0..47
    const int rg0 = rblk * 16 + wave * 4;

    f16x8 bh[4][8];
    #pragma unroll
    for (int rg = 0; rg < 4; ++rg) {
        const _Float16* p = ehh + (size_t)(rg0 + rg)*4096 + lane*8;
        #pragma unroll
        for (int s = 0; s < 8; ++s) bh[rg][s] = *(const f16x8*)(p + s*512);
    }
    const _Float16* gsrc = eth + (size_t)chunk * CTILES * 4096;

    #pragma unroll
    for (int i = 0; i < 2; ++i)
        gload_lds16(gsrc + (wave*2+i)*512 + lane*8, &abuf[0][(wave*2+i)*512]);
    #pragma unroll
    for (int i = 0; i < 2; ++i)
        gload_lds16(gsrc + 4096 + (wave*2+i)*512 + lane*8, &abuf[1][(wave*2+i)*512]);
    asm volatile("s_waitcnt vmcnt(2) lgkmcnt(0)" ::: "memory");
    __builtin_amdgcn_s_barrier();
    asm volatile("" ::: "memory");

    float gm[4] = {NEG_BIG, NEG_BIG, NEG_BIG, NEG_BIG};
    int cur = 0;
    for (int t = 0; t < CTILES; ++t) {
        int nx2 = cur - 1; if (nx2 < 0) nx2 = 2;
        if (t + 2 < CTILES) {
            #pragma unroll
            for (int i = 0; i < 2; ++i)
                gload_lds16(gsrc + (size_t)(t+2)*4096 + (wave*2+i)*512 + lane*8,
                            &abuf[nx2][(wave*2+i)*512]);
        }
        f32x4 aE[4], aO[4];
        #pragma unroll
        for (int rg = 0; rg < 4; ++rg) {
            aE[rg] = (f32x4){0.f,0.f,0.f,0.f};
            aO[rg] = (f32x4){0.f,0.f,0.f,0.f};
        }
        #pragma unroll
        for (int s = 0; s < 8; ++s) {
            f16x8 ah = *(const f16x8*)&abuf[cur][s*512 + lane*8];
            if (s & 1) {
                #pragma unroll
                for (int rg = 0; rg < 4; ++rg) aO[rg] = MFMA16(ah, bh[rg][s], aO[rg]);
            } else {
                #pragma unroll
                for (int rg = 0; rg < 4; ++rg) aE[rg] = MFMA16(ah, bh[rg][s], aE[rg]);
            }
        }
        #pragma unroll
        for (int rg = 0; rg < 4; ++rg) {
            f32x4 a = aE[rg] + aO[rg];
            float m = fmaxf(fmaxf(a[0],a[1]), fmaxf(a[2],a[3]));
            m = fmaxf(m, __shfl_xor(m, 16));
            m = fmaxf(m, __shfl_xor(m, 32));
            gm[rg] = (t & 1) ? fmaxf(gm[rg], m) : m;
        }
        if ((t & 1) && lane < 16) {
            #pragma unroll
            for (int rg = 0; rg < 4; ++rg) {
                float g = gm[rg];
                unsigned u = (__float_as_uint(g) >> 16) + (g < 0.f ? 1u : 0u);
                gml[(t>>1)*256 + wave*64 + rg*16 + lane] = (unsigned short)u;
            }
        }
        if (t + 2 < CTILES) { asm volatile("s_waitcnt vmcnt(2)" ::: "memory"); }
        else                { asm volatile("s_waitcnt vmcnt(0)" ::: "memory"); }
        __builtin_amdgcn_s_barrier();
        asm volatile("" ::: "memory");
        cur = (cur >= 2) ? 0 : cur + 1;
    }
    asm volatile("s_waitcnt lgkmcnt(0)" ::: "memory");
    __builtin_amdgcn_s_barrier();
    asm volatile("" ::: "memory");
    const int row0 = rblk * 256;
    for (int i = tid; i < NGRP*256; i += 256) {
        const int g = i >> 8, r = i & 255;
        gmax16[(size_t)(chunk*NGRP + g)*NROW + row0 + r] = gml[i];
    }
}

// ---------------------------------------------------------------------------
// B1: tau[row] = (12th-largest 32-col-group max) - margin.
// ---------------------------------------------------------------------------
__global__ __launch_bounds__(256) void b1_tau(
    const unsigned short* __restrict__ gmax16, float* __restrict__ tau)
{
    const int row = blockIdx.x * 256 + threadIdx.x;
    float tv[TK];
    #pragma unroll
    for (int j = 0; j < TK; ++j) tv[j] = NEG_BIG;
    for (int g = 0; g < 384; ++g) {
        unsigned short u = gmax16[(size_t)g*NROW + row];
        float v = __uint_as_float(((unsigned)u) << 16);
        #pragma unroll
        for (int j = TK-1; j >= 1; --j)
            tv[j] = __builtin_amdgcn_fmed3f(v, tv[j], tv[j-1]);
        tv[0] = fmaxf(v, tv[0]);
    }
    tau[row] = tv[TK-1] - 0.02f;
}

// ---------------------------------------------------------------------------
// S2: 1-term scores; collect columns >= tau[row] into LDS, flush once.
// Same grid/structure as S1.
// ---------------------------------------------------------------------------
#define S2CAP 1024
__global__ __launch_bounds__(256, 4) void s2_collect(
    const _Float16* __restrict__ ehh, const _Float16* __restrict__ eth,
    const float* __restrict__ tau, unsigned int* __restrict__ cnt,
    int* __restrict__ cand)
{
    __shared__ _Float16 abuf[3][4096];
    __shared__ int cmeta[S2CAP];
    __shared__ unsigned int lcnt;
    const int tid = threadIdx.x, lane = tid & 63, wave = tid >> 6;
    const int chunk = blockIdx.x & (NCH-1);
    const int rblk = blockIdx.x >> 4;
    const int rg0 = rblk * 16 + wave * 4;
    if (tid == 0) lcnt = 0;

    f16x8 bh[4][8];
    #pragma unroll
    for (int rg = 0; rg < 4; ++rg) {
        const _Float16* p = ehh + (size_t)(rg0 + rg)*4096 + lane*8;
        #pragma unroll
        for (int s = 0; s < 8; ++s) bh[rg][s] = *(const f16x8*)(p + s*512);
    }
    float tv[4];
    #pragma unroll
    for (int rg = 0; rg < 4; ++rg)
        tv[rg] = tau[rblk*256 + wave*64 + rg*16 + (lane & 15)];

    const _Float16* gsrc = eth + (size_t)chunk * CTILES * 4096;
    #pragma unroll
    for (int i = 0; i < 2; ++i)
        gload_lds16(gsrc + (wave*2+i)*512 + lane*8, &abuf[0][(wave*2+i)*512]);
    #pragma unroll
    for (int i = 0; i < 2; ++i)
        gload_lds16(gsrc + 4096 + (wave*2+i)*512 + lane*8, &abuf[1][(wave*2+i)*512]);
    asm volatile("s_waitcnt vmcnt(2) lgkmcnt(0)" ::: "memory");
    __builtin_amdgcn_s_barrier();
    asm volatile("" ::: "memory");

    int cur = 0;
    for (int t = 0; t < CTILES; ++t) {
        int nx2 = cur - 1; if (nx2 < 0) nx2 = 2;
        if (t + 2 < CTILES) {
            #pragma unroll
            for (int i = 0; i < 2; ++i)
                gload_lds16(gsrc + (size_t)(t+2)*4096 + (wave*2+i)*512 + lane*8,
                            &abuf[nx2][(wave*2+i)*512]);
        }
        f32x4 aE[4], aO[4];
        #pragma unroll
        for (int rg = 0; rg < 4; ++rg) {
            aE[rg] = (f32x4){0.f,0.f,0.f,0.f};
            aO[rg] = (f32x4){0.f,0.f,0.f,0.f};
        }
        #pragma unroll
        for (int s = 0; s < 8; ++s) {
            f16x8 ah = *(const f16x8*)&abuf[cur][s*512 + lane*8];
            if (s & 1) {
                #pragma unroll
                for (int rg = 0; rg < 4; ++rg) aO[rg] = MFMA16(ah, bh[rg][s], aO[rg]);
            } else {
                #pragma unroll
                for (int rg = 0; rg < 4; ++rg) aE[rg] = MFMA16(ah, bh[rg][s], aE[rg]);
            }
        }
        const int cb = (chunk*CTILES + t)*16 + 4*(lane >> 4);
        #pragma unroll
        for (int rg = 0; rg < 4; ++rg) {
            f32x4 a = aE[rg] + aO[rg];
            float m = fmaxf(fmaxf(a[0],a[1]), fmaxf(a[2],a[3]));
            if (__any(m >= tv[rg])) {
                const int lrow = wave*64 + rg*16 + (lane & 15);
                #pragma unroll
                for (int e = 0; e < 4; ++e) {
                    if (a[e] >= tv[rg]) {
                        unsigned p = atomicAdd(&lcnt, 1u);
                        if (p < S2CAP) cmeta[p] = (cb + e) | (lrow << 16);
                    }
                }
            }
        }
        if (t + 2 < CTILES) { asm volatile("s_waitcnt vmcnt(2)" ::: "memory"); }
        else                { asm volatile("s_waitcnt vmcnt(0)" ::: "memory"); }
        __builtin_amdgcn_s_barrier();
        asm volatile("" ::: "memory");
        cur = (cur >= 2) ? 0 : cur + 1;
    }
    asm volatile("s_waitcnt lgkmcnt(0)" ::: "memory");
    __builtin_amdgcn_s_barrier();
    asm volatile("" ::: "memory");
    const int row0 = rblk * 256;
    const unsigned n = (lcnt < (unsigned)S2CAP) ? lcnt : (unsigned)S2CAP;
    for (unsigned i = tid; i < n; i += 256) {
        const int m = cmeta[i];
        const int row = row0 + (m >> 16);
        unsigned p = atomicAdd(&cnt[row], 1u);
        if (p < 64) cand[(size_t)row*64 + p] = m & 0xffff;
    }
}

// ---------------------------------------------------------------------------
// S3: exact f32 rescoring of candidates, top-12 (val desc, col asc),
// softmax / gather / tanh-gate / ka-softmax / e_Nh. One wave per row.
// ---------------------------------------------------------------------------
__global__ __launch_bounds__(256) void s3_tail(
    const float* __restrict__ e_h, const float* __restrict__ e_t,
    const unsigned int* __restrict__ cnt, const int* __restrict__ cand,
    float* __restrict__ e_Nh)
{
    const int lane = threadIdx.x & 63;
    const int wave = threadIdx.x >> 6;
    const int row  = blockIdx.x * 4 + wave;

    const unsigned cn = min(cnt[row], 64u);
    const bool act = lane < (int)cn;
    int colc = act ? cand[(size_t)row*64 + lane] : 0x7fffffff;

    const float* ehr = e_h + (size_t)row * 256;
    const float* etr = e_t + (size_t)(act ? colc : 0) * 256;
    float s = 0.f;
    for (int k = 0; k < 64; ++k) {
        float4 a = *(const float4*)(ehr + k*4);
        float4 b = *(const float4*)(etr + k*4);
        s += a.x*b.x + a.y*b.y + a.z*b.z + a.w*b.w;
    }
    s *= 0.0625f;
    if (!act) s = NEG_BIG;

    float tvv[TK]; int ti[TK];
    float v = s; int c = colc;
    #pragma unroll
    for (int o = 0; o < TK; ++o) {
        float bv = v; int bc = c;
        #pragma unroll
        for (int off = 32; off; off >>= 1) {
            float ov = __shfl_xor(bv, off);
            int   oc = __shfl_xor(bc, off);
            bool take = (ov > bv) || (ov == bv && oc < bc);
            bv = take ? ov : bv;
            bc = take ? oc : bc;
        }
        tvv[o] = bv; ti[o] = bc;
        if (c == bc) v = NEG_BIG;
    }

    float p[TK]; float Z = 0.f;
    #pragma unroll
    for (int j = 0; j < TK; ++j) { p[j] = expf(tvv[j] - tvv[0]); Z += p[j]; }
    const float invZ = 1.f / Z;
    #pragma unroll
    for (int j = 0; j < TK; ++j) p[j] *= invZ;

    float4 eh = *(const float4*)(ehr + lane * 4);

    float4 nb[TK]; float kw[TK];
    #pragma unroll
    for (int k = 0; k < TK; ++k) {
        float4 n = *(const float4*)(e_t + (size_t)ti[k] * 256 + lane * 4);
        nb[k] = n;
        const float pk = p[k], qk = 1.f - p[k];
        float4 gt;
        gt.x = tanhf(eh.x + (pk * n.x + qk * eh.x));
        gt.y = tanhf(eh.y + (pk * n.y + qk * eh.y));
        gt.z = tanhf(eh.z + (pk * n.z + qk * eh.z));
        gt.w = tanhf(eh.w + (pk * n.w + qk * eh.w));
        float d = n.x*gt.x + n.y*gt.y + n.z*gt.z + n.w*gt.w;
        #pragma unroll
        for (int off = 32; off; off >>= 1) d += __shfl_xor(d, off);
        kw[k] = d;
    }

    float km = kw[0];
    #pragma unroll
    for (int k = 1; k < TK; ++k) km = fmaxf(km, kw[k]);
    float kz = 0.f; float kp[TK];
    #pragma unroll
    for (int k = 0; k < TK; ++k) { kp[k] = expf(kw[k] - km); kz += kp[k]; }
    const float invKZ = 1.f / kz;

    float4 acc = make_float4(0.f, 0.f, 0.f, 0.f);
    #pragma unroll
    for (int k = 0; k < TK; ++k) {
        acc.x += kp[k] * nb[k].x;
        acc.y += kp[k] * nb[k].y;
        acc.z += kp[k] * nb[k].z;
        acc.w += kp[k] * nb[k].w;
    }
    acc.x *= invKZ; acc.y *= invKZ; acc.z *= invKZ; acc.w *= invKZ;
    *(float4*)(e_Nh + (size_t)row * 256 + lane * 4) = acc;
}

// ---------------------------------------------------------------------------
extern "C" void kernel_launch(void* const* d_in, const int* in_sizes, int n_in,
                              void* d_out, int out_size, void* d_ws, size_t ws_size,
                              hipStream_t stream)
{
    (void)in_sizes; (void)n_in; (void)out_size; (void)ws_size;
    const float* x     = (const float*)d_in[0];
    const float* wsi_w = (const float*)d_in[1];
    const float* wsi_b = (const float*)d_in[2];
    const float* wh_w  = (const float*)d_in[3];
    const float* wh_b  = (const float*)d_in[4];
    const float* wt_w  = (const float*)d_in[5];
    const float* wt_b  = (const float*)d_in[6];
    const float* w1_w  = (const float*)d_in[7];
    const float* w1_b  = (const float*)d_in[8];
    const float* w2_w  = (const float*)d_in[9];
    const float* w2_b  = (const float*)d_in[10];
    float* out = (float*)d_out;
    float* ws  = (float*)d_ws;

    const int M = NROW;
    const size_t ND = (size_t)M * 256;            // 3,145,728

    float* h    = ws;                             // reused as e_Nh
    float* e_h  = ws + ND;
    float* e_t  = ws + 2*ND;
    _Float16* ehh = (_Float16*)(ws + 3*ND);       // ND halfs
    _Float16* eth = (_Float16*)(ws + 3*ND + ND/2);
    size_t o = 4*ND;
    unsigned short* gmax16 = (unsigned short*)(ws + o); o += (size_t)384*NROW/2;
    float* tau = ws + o;                          o += NROW;
    unsigned int* cnt = (unsigned int*)(ws + o);  o += NROW;
    int* cand = (int*)(ws + o);                   o += (size_t)NROW*64;
    _Float16* hp = (_Float16*)(ws + o);
    _Float16* wsiH = hp;                 // 1024*256 halfs
    _Float16* wsiL = hp + 262144;
    _Float16* whH  = hp + 524288;        // 256*256 each below
    _Float16* whL  = hp + 524288 + 65536;
    _Float16* wtH  = hp + 524288 + 2*65536;
    _Float16* wtL  = hp + 524288 + 3*65536;
    _Float16* w1H  = hp + 524288 + 4*65536;
    _Float16* w1L  = hp + 524288 + 5*65536;
    _Float16* w2H  = hp + 524288 + 6*65536;
    _Float16* w2L  = hp + 524288 + 7*65536;
    float* e_Nh = h;

    // pack weights into fragment layout
    wpack<<<128, 256, 0, stream>>>(wsi_w, wsiH, wsiL, 256, 32);
    wpack<<<32, 256, 0, stream>>>(wh_w, whH, whL, 256, 8);
    wpack<<<32, 256, 0, stream>>>(wt_w, wtH, wtL, 256, 8);
    wpack<<<32, 256, 0, stream>>>(w1_w, w1H, w1L, 256, 8);
    wpack<<<32, 256, 0, stream>>>(w2_w, w2H, w2L, 256, 8);

    // K1: h = relu(x @ wsi + b)
    gemm_mfma<true><<<dim3(2, M/64), 256, 0, stream>>>(
        x, wsiH, wsiL, wsi_b, h, 1024);
    // K2 fused: e_h = h@wh + bh ; e_t = h@wt + bt
    gemm_dual<0><<<dim3(2, M/64), 256, 0, stream>>>(
        h, nullptr, whH, whL, wtH, wtL, wh_b, wt_b, e_h, e_t);
    // pack activations (hi only)
    pack_hi<<<1536, 256, 0, stream>>>(e_h, ehh, 0.0625f);
    pack_hi<<<1536, 256, 0, stream>>>(e_t, eth, 1.0f);
    // S1 / B1 / S2 / S3
    s1_gmax<<<NCH*48, 256, 0, stream>>>(ehh, eth, gmax16);
    b1_tau<<<M/256, 256, 0, stream>>>(gmax16, tau);
    hipMemsetAsync(cnt, 0, (size_t)M*sizeof(unsigned int), stream);
    s2_collect<<<NCH*48, 256, 0, stream>>>(ehh, eth, tau, cnt, cand);
    s3_tail<<<M/4, 256, 0, stream>>>(e_h, e_t, cnt, cand, e_Nh);
    // K5 fused: out = relu((e_h+e_Nh)@w1+b1) + relu((e_h*e_Nh)@w2+b2)
    gemm_dual<1><<<dim3(2, M/64), 256, 0, stream>>>(
        e_h, e_Nh, w1H, w1L, w2H, w2L, w1_b, w2_b, out, nullptr);
}

// Round 7
// 412.903 us; speedup vs baseline: 2.0789x; 2.0789x over previous
//
#include <hip/hip_runtime.h>
#include <hip/hip_bf16.h>
#include <cmath>

#define TK 12
#define NROW 12288
#define NEG_BIG (-3.0e38f)
#define MFMA16(a,b,c) __builtin_amdgcn_mfma_f32_16x16x32_f16(a,b,c,0,0,0)

// 8 column chunks of 1536 cols = 96 tiles of 16 cols; 48 32-col groups/chunk
#define NCH 8
#define CTILES 96
#define NGRP 48

typedef _Float16 f16x8 __attribute__((ext_vector_type(8)));
typedef float    f32x4 __attribute__((ext_vector_type(4)));

typedef __attribute__((address_space(1))) const void gvoid_t;
typedef __attribute__((address_space(3))) void lvoid_t;
__device__ __forceinline__ void gload_lds16(const void* g, void* l) {
    __builtin_amdgcn_global_load_lds((gvoid_t*)g, (lvoid_t*)l, 16, 0, 0);
}

// ---------------------------------------------------------------------------
// wpack: W [K][N] f32 -> A-operand fragments of W^T, hi/lo f16.
// P[cg][s][l][j] = W[s*32 + 8*(l>>4) + j][cg*16 + (l&15)], linear idx = tid*8.
// ---------------------------------------------------------------------------
__global__ __launch_bounds__(256) void wpack(
    const float* __restrict__ W, _Float16* __restrict__ hi,
    _Float16* __restrict__ lo, int N, int nkt)
{
    const int tid = blockIdx.x * 256 + threadIdx.x;
    const int l = tid & 63;
    const int s = (tid >> 6) % nkt;
    const int cg = tid / (nkt * 64);
    const int krow = s * 32 + 8 * (l >> 4);
    const int col = cg * 16 + (l & 15);
    f16x8 H, L;
    #pragma unroll
    for (int j = 0; j < 8; ++j) {
        float w = W[(size_t)(krow + j) * N + col];
        _Float16 h = (_Float16)w;
        H[j] = h;
        L[j] = (_Float16)(w - (float)h);
    }
    *(f16x8*)(hi + (size_t)tid * 8) = H;
    *(f16x8*)(lo + (size_t)tid * 8) = L;
}

// ---------------------------------------------------------------------------
// gemm_mfma (K1): C = relu?( A @ W + bias ). Grid (4,192) = 768 blocks.
// Block = 64 rows x 64 cols; wave owns 1 colgroup x 64 rows.
// ---------------------------------------------------------------------------
template<bool RELU>
__global__ __launch_bounds__(256) void gemm_mfma(
    const float* __restrict__ A1,
    const _Float16* __restrict__ Wh, const _Float16* __restrict__ Wl,
    const float* __restrict__ bias, float* __restrict__ C, int K)
{
    __shared__ _Float16 aH[2048], aL[2048];
    __shared__ _Float16 wH[2048], wL[2048];
    const int tid = threadIdx.x, lane = tid & 63, wave = tid >> 6;
    const int rb = blockIdx.y * 64;
    const int cbg = blockIdx.x * 4;
    const int nkt = K >> 5;

    const int arow = rb + wave * 16 + (lane & 15);
    const int acol0 = 8 * (lane >> 4);
    const float* a1p = A1 + (size_t)arow * K + acol0;

    f32x4 acc[4];
    #pragma unroll
    for (int rg = 0; rg < 4; ++rg) acc[rg] = (f32x4){0.f,0.f,0.f,0.f};

    for (int kt = 0; kt < nkt; ++kt) {
        __syncthreads();
        {
            float v[8];
            *(float4*)v       = *(const float4*)(a1p + kt*32);
            *(float4*)(v + 4) = *(const float4*)(a1p + kt*32 + 4);
            f16x8 H, L;
            #pragma unroll
            for (int j = 0; j < 8; ++j) {
                _Float16 h = (_Float16)v[j];
                H[j] = h;
                L[j] = (_Float16)(v[j] - (float)h);
            }
            *(f16x8*)&aH[tid*8] = H;
            *(f16x8*)&aL[tid*8] = L;
        }
        {
            const size_t goff = ((size_t)(cbg + (tid >> 6)) * nkt + kt) * 512 + (tid & 63)*8;
            *(f16x8*)&wH[tid*8] = *(const f16x8*)(Wh + goff);
            *(f16x8*)&wL[tid*8] = *(const f16x8*)(Wl + goff);
        }
        __syncthreads();
        f16x8 wh = *(const f16x8*)&wH[(wave*64 + lane)*8];
        f16x8 wl = *(const f16x8*)&wL[(wave*64 + lane)*8];
        #pragma unroll
        for (int rg = 0; rg < 4; ++rg) {
            f16x8 ah = *(const f16x8*)&aH[(rg*64 + lane)*8];
            f16x8 al = *(const f16x8*)&aL[(rg*64 + lane)*8];
            acc[rg] = MFMA16(wh, ah, acc[rg]);
            acc[rg] = MFMA16(wl, ah, acc[rg]);
            acc[rg] = MFMA16(wh, al, acc[rg]);
        }
    }
    const int col = (cbg + wave)*16 + 4*(lane >> 4);
    float4 b4 = *(const float4*)(bias + col);
    #pragma unroll
    for (int rg = 0; rg < 4; ++rg) {
        const int row = rb + rg*16 + (lane & 15);
        float4 o;
        o.x = acc[rg][0] + b4.x; o.y = acc[rg][1] + b4.y;
        o.z = acc[rg][2] + b4.z; o.w = acc[rg][3] + b4.w;
        if (RELU) {
            o.x = fmaxf(o.x, 0.f); o.y = fmaxf(o.y, 0.f);
            o.z = fmaxf(o.z, 0.f); o.w = fmaxf(o.w, 0.f);
        }
        *(float4*)(C + (size_t)row*256 + col) = o;
    }
}

// ---------------------------------------------------------------------------
// gemm_dual: K=N=256 fused pair. Grid (4,192) = 768 blocks; wave owns 1 cg.
//  DMODE 0: C1 = A1@W1 + b1 ; C2 = A1@W2 + b2
//  DMODE 1: C1 = relu((A1+A2)@W1+b1) + relu((A1*A2)@W2+b2)
// ---------------------------------------------------------------------------
template<int DMODE>
__global__ __launch_bounds__(256) void gemm_dual(
    const float* __restrict__ A1, const float* __restrict__ A2,
    const _Float16* __restrict__ W1h, const _Float16* __restrict__ W1l,
    const _Float16* __restrict__ W2h, const _Float16* __restrict__ W2l,
    const float* __restrict__ bias1, const float* __restrict__ bias2,
    float* __restrict__ C1, float* __restrict__ C2)
{
    __shared__ _Float16 aH[2][2048], aL[2][2048];
    __shared__ _Float16 wH[2][2048], wL[2][2048];
    const int tid = threadIdx.x, lane = tid & 63, wave = tid >> 6;
    const int rb = blockIdx.y * 64;
    const int cbg = blockIdx.x * 4;

    const int arow = rb + wave * 16 + (lane & 15);
    const int acol0 = 8 * (lane >> 4);
    const float* a1p = A1 + (size_t)arow * 256 + acol0;
    const float* a2p = (DMODE == 1) ? (A2 + (size_t)arow * 256 + acol0) : nullptr;

    f32x4 acc1[4], acc2[4];
    #pragma unroll
    for (int rg = 0; rg < 4; ++rg) {
        acc1[rg] = (f32x4){0.f,0.f,0.f,0.f};
        acc2[rg] = (f32x4){0.f,0.f,0.f,0.f};
    }

    for (int kt = 0; kt < 8; ++kt) {
        __syncthreads();
        {
            float v[8];
            *(float4*)v       = *(const float4*)(a1p + kt*32);
            *(float4*)(v + 4) = *(const float4*)(a1p + kt*32 + 4);
            if (DMODE == 0) {
                f16x8 H, L;
                #pragma unroll
                for (int j = 0; j < 8; ++j) {
                    _Float16 h = (_Float16)v[j];
                    H[j] = h;
                    L[j] = (_Float16)(v[j] - (float)h);
                }
                *(f16x8*)&aH[0][tid*8] = H;
                *(f16x8*)&aL[0][tid*8] = L;
            } else {
                float b[8];
                *(float4*)b       = *(const float4*)(a2p + kt*32);
                *(float4*)(b + 4) = *(const float4*)(a2p + kt*32 + 4);
                f16x8 Hs, Ls, Hm, Lm;
                #pragma unroll
                for (int j = 0; j < 8; ++j) {
                    float s = v[j] + b[j];
                    float m = v[j] * b[j];
                    _Float16 hs = (_Float16)s;
                    _Float16 hm = (_Float16)m;
                    Hs[j] = hs; Ls[j] = (_Float16)(s - (float)hs);
                    Hm[j] = hm; Lm[j] = (_Float16)(m - (float)hm);
                }
                *(f16x8*)&aH[0][tid*8] = Hs;
                *(f16x8*)&aL[0][tid*8] = Ls;
                *(f16x8*)&aH[1][tid*8] = Hm;
                *(f16x8*)&aL[1][tid*8] = Lm;
            }
        }
        {
            const size_t goff = ((size_t)(cbg + (tid >> 6)) * 8 + kt) * 512 + (tid & 63)*8;
            *(f16x8*)&wH[0][tid*8] = *(const f16x8*)(W1h + goff);
            *(f16x8*)&wL[0][tid*8] = *(const f16x8*)(W1l + goff);
            *(f16x8*)&wH[1][tid*8] = *(const f16x8*)(W2h + goff);
            *(f16x8*)&wL[1][tid*8] = *(const f16x8*)(W2l + goff);
        }
        __syncthreads();
        f16x8 w1h = *(const f16x8*)&wH[0][(wave*64 + lane)*8];
        f16x8 w1l = *(const f16x8*)&wL[0][(wave*64 + lane)*8];
        f16x8 w2h = *(const f16x8*)&wH[1][(wave*64 + lane)*8];
        f16x8 w2l = *(const f16x8*)&wL[1][(wave*64 + lane)*8];
        #pragma unroll
        for (int rg = 0; rg < 4; ++rg) {
            f16x8 ah0 = *(const f16x8*)&aH[0][(rg*64 + lane)*8];
            f16x8 al0 = *(const f16x8*)&aL[0][(rg*64 + lane)*8];
            acc1[rg] = MFMA16(w1h, ah0, acc1[rg]);
            acc1[rg] = MFMA16(w1l, ah0, acc1[rg]);
            acc1[rg] = MFMA16(w1h, al0, acc1[rg]);
            f16x8 ah1 = (DMODE == 1) ? *(const f16x8*)&aH[1][(rg*64 + lane)*8] : ah0;
            f16x8 al1 = (DMODE == 1) ? *(const f16x8*)&aL[1][(rg*64 + lane)*8] : al0;
            acc2[rg] = MFMA16(w2h, ah1, acc2[rg]);
            acc2[rg] = MFMA16(w2l, ah1, acc2[rg]);
            acc2[rg] = MFMA16(w2h, al1, acc2[rg]);
        }
    }
    const int col = (cbg + wave)*16 + 4*(lane >> 4);
    float4 b14 = *(const float4*)(bias1 + col);
    float4 b24 = *(const float4*)(bias2 + col);
    #pragma unroll
    for (int rg = 0; rg < 4; ++rg) {
        const int row = rb + rg*16 + (lane & 15);
        if (DMODE == 0) {
            float4 o1, o2;
            o1.x = acc1[rg][0] + b14.x; o1.y = acc1[rg][1] + b14.y;
            o1.z = acc1[rg][2] + b14.z; o1.w = acc1[rg][3] + b14.w;
            o2.x = acc2[rg][0] + b24.x; o2.y = acc2[rg][1] + b24.y;
            o2.z = acc2[rg][2] + b24.z; o2.w = acc2[rg][3] + b24.w;
            *(float4*)(C1 + (size_t)row*256 + col) = o1;
            *(float4*)(C2 + (size_t)row*256 + col) = o2;
        } else {
            float4 o;
            o.x = fmaxf(acc1[rg][0] + b14.x, 0.f) + fmaxf(acc2[rg][0] + b24.x, 0.f);
            o.y = fmaxf(acc1[rg][1] + b14.y, 0.f) + fmaxf(acc2[rg][1] + b24.y, 0.f);
            o.z = fmaxf(acc1[rg][2] + b14.z, 0.f) + fmaxf(acc2[rg][2] + b24.z, 0.f);
            o.w = fmaxf(acc1[rg][3] + b14.w, 0.f) + fmaxf(acc2[rg][3] + b24.w, 0.f);
            *(float4*)(C1 + (size_t)row*256 + col) = o;
        }
    }
}

// ---------------------------------------------------------------------------
// pack_hi: X f32 [12288][256] (scaled) -> hi f16 in MFMA fragment order.
// ---------------------------------------------------------------------------
__global__ __launch_bounds__(256) void pack_hi(
    const float* __restrict__ X, _Float16* __restrict__ hi, float scale)
{
    const int tid = blockIdx.x * 256 + threadIdx.x;
    const int g = tid >> 9;
    const int rem = tid & 511;
    const int s = rem >> 6, l = rem & 63;
    const float* src = X + (size_t)(g*16 + (l & 15))*256 + s*32 + 8*(l >> 4);
    float4 v0 = *(const float4*)src;
    float4 v1 = *(const float4*)(src + 4);
    float vv[8] = {v0.x, v0.y, v0.z, v0.w, v1.x, v1.y, v1.z, v1.w};
    f16x8 H;
    #pragma unroll
    for (int j = 0; j < 8; ++j) H[j] = (_Float16)(vv[j] * scale);
    *(f16x8*)(hi + (size_t)tid * 8) = H;
}

// ---------------------------------------------------------------------------
// S1: per-(row, 32-col-group) maxima, 1-term f16, + per-chunk sorted top-12
// of group maxima. Grid = 8 chunks x 96 rowblocks = 768 blocks (3/CU).
// Block = 4 waves x 32 rows = 128 rows x 1536-col chunk. bh[2][8] (64 VGPR)
// pinned via opaque asm. Triple-buffered global_load_lds + counted vmcnt.
// ---------------------------------------------------------------------------
__global__ __launch_bounds__(256) void s1_gmax(
    const _Float16* __restrict__ ehh, const _Float16* __restrict__ eth,
    float* __restrict__ tau12)
{
    __shared__ _Float16 abuf[3][4096];          // 3 x 8KB tiles
    __shared__ unsigned short gml[NGRP * 128];  // 12KB
    const int tid = threadIdx.x, lane = tid & 63, wave = tid >> 6;
    const int chunk = blockIdx.x & (NCH-1);     // == XCD id (L2 affinity)
    const int rblk = blockIdx.x >> 3;           // 0..95
    const int rg0 = rblk * 8 + wave * 2;

    f32x4 bh[2][8];
    #pragma unroll
    for (int rs = 0; rs < 2; ++rs) {
        const _Float16* p = ehh + (size_t)(rg0 + rs)*4096 + lane*8;
        #pragma unroll
        for (int s = 0; s < 8; ++s) bh[rs][s] = *(const f32x4*)(p + s*512);
    }
    // pin fragments in VGPRs (prevent remat-from-global; round-6 lesson)
    #pragma unroll
    for (int rs = 0; rs < 2; ++rs)
        #pragma unroll
        for (int s = 0; s < 8; ++s)
            asm volatile("" : "+v"(bh[rs][s]));

    const _Float16* gsrc = eth + (size_t)chunk * CTILES * 4096;
    #pragma unroll
    for (int i = 0; i < 2; ++i)
        gload_lds16(gsrc + (wave*2+i)*512 + lane*8, &abuf[0][(wave*2+i)*512]);
    #pragma unroll
    for (int i = 0; i < 2; ++i)
        gload_lds16(gsrc + 4096 + (wave*2+i)*512 + lane*8, &abuf[1][(wave*2+i)*512]);
    asm volatile("s_waitcnt vmcnt(2) lgkmcnt(0)" ::: "memory");
    __builtin_amdgcn_s_barrier();
    asm volatile("" ::: "memory");

    float gm[2] = {NEG_BIG, NEG_BIG};
    int cur = 0;
    for (int t = 0; t < CTILES; ++t) {
        int nx2 = cur - 1; if (nx2 < 0) nx2 = 2;
        if (t + 2 < CTILES) {
            #pragma unroll
            for (int i = 0; i < 2; ++i)
                gload_lds16(gsrc + (size_t)(t+2)*4096 + (wave*2+i)*512 + lane*8,
                            &abuf[nx2][(wave*2+i)*512]);
        }
        f32x4 aE[2], aO[2];
        #pragma unroll
        for (int rs = 0; rs < 2; ++rs) {
            aE[rs] = (f32x4){0.f,0.f,0.f,0.f};
            aO[rs] = (f32x4){0.f,0.f,0.f,0.f};
        }
        #pragma unroll
        for (int s = 0; s < 8; ++s) {
            f16x8 ah = *(const f16x8*)&abuf[cur][s*512 + lane*8];
            if (s & 1) {
                #pragma unroll
                for (int rs = 0; rs < 2; ++rs)
                    aO[rs] = MFMA16(ah, __builtin_bit_cast(f16x8, bh[rs][s]), aO[rs]);
            } else {
                #pragma unroll
                for (int rs = 0; rs < 2; ++rs)
                    aE[rs] = MFMA16(ah, __builtin_bit_cast(f16x8, bh[rs][s]), aE[rs]);
            }
        }
        #pragma unroll
        for (int rs = 0; rs < 2; ++rs) {
            f32x4 a = aE[rs] + aO[rs];
            float m = fmaxf(fmaxf(a[0],a[1]), fmaxf(a[2],a[3]));
            m = fmaxf(m, __shfl_xor(m, 16));
            m = fmaxf(m, __shfl_xor(m, 32));
            gm[rs] = (t & 1) ? fmaxf(gm[rs], m) : m;
        }
        if ((t & 1) && lane < 16) {
            #pragma unroll
            for (int rs = 0; rs < 2; ++rs) {
                float g = gm[rs];
                unsigned u = (__float_as_uint(g) >> 16) + (g < 0.f ? 1u : 0u);
                gml[(t>>1)*128 + wave*32 + rs*16 + lane] = (unsigned short)u;
            }
        }
        if (t + 2 < CTILES) { asm volatile("s_waitcnt vmcnt(2)" ::: "memory"); }
        else                { asm volatile("s_waitcnt vmcnt(0)" ::: "memory"); }
        __builtin_amdgcn_s_barrier();
        asm volatile("" ::: "memory");
        cur = (cur >= 2) ? 0 : cur + 1;
    }
    asm volatile("s_waitcnt lgkmcnt(0)" ::: "memory");
    __builtin_amdgcn_s_barrier();
    asm volatile("" ::: "memory");
    // per-row sorted top-12 of this chunk's 48 group maxima
    if (tid < 128) {
        float tv[TK];
        #pragma unroll
        for (int j = 0; j < TK; ++j) tv[j] = NEG_BIG;
        for (int g = 0; g < NGRP; ++g) {
            float v = __uint_as_float(((unsigned)gml[g*128 + tid]) << 16);
            #pragma unroll
            for (int j = TK-1; j >= 1; --j)
                tv[j] = __builtin_amdgcn_fmed3f(v, tv[j], tv[j-1]);
            tv[0] = fmaxf(v, tv[0]);
        }
        float* op = tau12 + ((size_t)chunk*NROW + rblk*128 + tid)*TK;
        #pragma unroll
        for (int j = 0; j < TK; ++j) op[j] = tv[j];
    }
}

// ---------------------------------------------------------------------------
// B1: tau[row] = 12th-largest of the union of 8 per-chunk top-12 lists, - margin.
// ---------------------------------------------------------------------------
__global__ __launch_bounds__(256) void b1_tau(
    const float* __restrict__ tau12, float* __restrict__ tau)
{
    const int row = blockIdx.x * 256 + threadIdx.x;
    float tv[TK];
    #pragma unroll
    for (int j = 0; j < TK; ++j) tv[j] = NEG_BIG;
    #pragma unroll 1
    for (int c = 0; c < NCH; ++c) {
        const float* p = tau12 + ((size_t)c*NROW + row)*TK;
        float4 q0 = *(const float4*)p;
        float4 q1 = *(const float4*)(p + 4);
        float4 q2 = *(const float4*)(p + 8);
        float vv[TK] = {q0.x,q0.y,q0.z,q0.w, q1.x,q1.y,q1.z,q1.w, q2.x,q2.y,q2.z,q2.w};
        #pragma unroll
        for (int i = 0; i < TK; ++i) {
            float v = vv[i];
            #pragma unroll
            for (int j = TK-1; j >= 1; --j)
                tv[j] = __builtin_amdgcn_fmed3f(v, tv[j], tv[j-1]);
            tv[0] = fmaxf(v, tv[0]);
        }
    }
    tau[row] = tv[TK-1] - 0.02f;
}

// ---------------------------------------------------------------------------
// S2: 1-term scores; collect columns >= tau[row] into LDS, flush once.
// Same geometry as S1 (128 rows/block, 8 chunks x 96 rowblocks).
// ---------------------------------------------------------------------------
#define S2CAP 1024
__global__ __launch_bounds__(256) void s2_collect(
    const _Float16* __restrict__ ehh, const _Float16* __restrict__ eth,
    const float* __restrict__ tau, unsigned int* __restrict__ cnt,
    int* __restrict__ cand)
{
    __shared__ _Float16 abuf[3][4096];
    __shared__ int cmeta[S2CAP];
    __shared__ unsigned int lcnt;
    const int tid = threadIdx.x, lane = tid & 63, wave = tid >> 6;
    const int chunk = blockIdx.x & (NCH-1);
    const int rblk = blockIdx.x >> 3;
    const int rg0 = rblk * 8 + wave * 2;
    if (tid == 0) lcnt = 0;

    f32x4 bh[2][8];
    #pragma unroll
    for (int rs = 0; rs < 2; ++rs) {
        const _Float16* p = ehh + (size_t)(rg0 + rs)*4096 + lane*8;
        #pragma unroll
        for (int s = 0; s < 8; ++s) bh[rs][s] = *(const f32x4*)(p + s*512);
    }
    #pragma unroll
    for (int rs = 0; rs < 2; ++rs)
        #pragma unroll
        for (int s = 0; s < 8; ++s)
            asm volatile("" : "+v"(bh[rs][s]));

    float tvr[2];
    #pragma unroll
    for (int rs = 0; rs < 2; ++rs)
        tvr[rs] = tau[rblk*128 + wave*32 + rs*16 + (lane & 15)];

    const _Float16* gsrc = eth + (size_t)chunk * CTILES * 4096;
    #pragma unroll
    for (int i = 0; i < 2; ++i)
        gload_lds16(gsrc + (wave*2+i)*512 + lane*8, &abuf[0][(wave*2+i)*512]);
    #pragma unroll
    for (int i = 0; i < 2; ++i)
        gload_lds16(gsrc + 4096 + (wave*2+i)*512 + lane*8, &abuf[1][(wave*2+i)*512]);
    asm volatile("s_waitcnt vmcnt(2) lgkmcnt(0)" ::: "memory");
    __builtin_amdgcn_s_barrier();
    asm volatile("" ::: "memory");

    int cur = 0;
    for (int t = 0; t < CTILES; ++t) {
        int nx2 = cur - 1; if (nx2 < 0) nx2 = 2;
        if (t + 2 < CTILES) {
            #pragma unroll
            for (int i = 0; i < 2; ++i)
                gload_lds16(gsrc + (size_t)(t+2)*4096 + (wave*2+i)*512 + lane*8,
                            &abuf[nx2][(wave*2+i)*512]);
        }
        f32x4 aE[2], aO[2];
        #pragma unroll
        for (int rs = 0; rs < 2; ++rs) {
            aE[rs] = (f32x4){0.f,0.f,0.f,0.f};
            aO[rs] = (f32x4){0.f,0.f,0.f,0.f};
        }
        #pragma unroll
        for (int s = 0; s < 8; ++s) {
            f16x8 ah = *(const f16x8*)&abuf[cur][s*512 + lane*8];
            if (s & 1) {
                #pragma unroll
                for (int rs = 0; rs < 2; ++rs)
                    aO[rs] = MFMA16(ah, __builtin_bit_cast(f16x8, bh[rs][s]), aO[rs]);
            } else {
                #pragma unroll
                for (int rs = 0; rs < 2; ++rs)
                    aE[rs] = MFMA16(ah, __builtin_bit_cast(f16x8, bh[rs][s]), aE[rs]);
            }
        }
        const int cb = (chunk*CTILES + t)*16 + 4*(lane >> 4);
        #pragma unroll
        for (int rs = 0; rs < 2; ++rs) {
            f32x4 a = aE[rs] + aO[rs];
            float m = fmaxf(fmaxf(a[0],a[1]), fmaxf(a[2],a[3]));
            if (__any(m >= tvr[rs])) {
                const int lrow = wave*32 + rs*16 + (lane & 15);
                #pragma unroll
                for (int e = 0; e < 4; ++e) {
                    if (a[e] >= tvr[rs]) {
                        unsigned p = atomicAdd(&lcnt, 1u);
                        if (p < S2CAP) cmeta[p] = (cb + e) | (lrow << 16);
                    }
                }
            }
        }
        if (t + 2 < CTILES) { asm volatile("s_waitcnt vmcnt(2)" ::: "memory"); }
        else                { asm volatile("s_waitcnt vmcnt(0)" ::: "memory"); }
        __builtin_amdgcn_s_barrier();
        asm volatile("" ::: "memory");
        cur = (cur >= 2) ? 0 : cur + 1;
    }
    asm volatile("s_waitcnt lgkmcnt(0)" ::: "memory");
    __builtin_amdgcn_s_barrier();
    asm volatile("" ::: "memory");
    const int row0 = rblk * 128;
    const unsigned n = (lcnt < (unsigned)S2CAP) ? lcnt : (unsigned)S2CAP;
    for (unsigned i = tid; i < n; i += 256) {
        const int m = cmeta[i];
        const int row = row0 + (m >> 16);
        unsigned p = atomicAdd(&cnt[row], 1u);
        if (p < 64) cand[(size_t)row*64 + p] = m & 0xffff;
    }
}

// ---------------------------------------------------------------------------
// S3: exact f32 rescoring of candidates, top-12 (val desc, col asc),
// softmax / gather / tanh-gate / ka-softmax / e_Nh. One wave per row.
// ---------------------------------------------------------------------------
__global__ __launch_bounds__(256) void s3_tail(
    const float* __restrict__ e_h, const float* __restrict__ e_t,
    const unsigned int* __restrict__ cnt, const int* __restrict__ cand,
    float* __restrict__ e_Nh)
{
    const int lane = threadIdx.x & 63;
    const int wave = threadIdx.x >> 6;
    const int row  = blockIdx.x * 4 + wave;

    const unsigned cn = min(cnt[row], 64u);
    const bool act = lane < (int)cn;
    int colc = act ? cand[(size_t)row*64 + lane] : 0x7fffffff;

    const float* ehr = e_h + (size_t)row * 256;
    const float* etr = e_t + (size_t)(act ? colc : 0) * 256;
    float s = 0.f;
    for (int k = 0; k < 64; ++k) {
        float4 a = *(const float4*)(ehr + k*4);
        float4 b = *(const float4*)(etr + k*4);
        s += a.x*b.x + a.y*b.y + a.z*b.z + a.w*b.w;
    }
    s *= 0.0625f;
    if (!act) s = NEG_BIG;

    float tvv[TK]; int ti[TK];
    float v = s; int c = colc;
    #pragma unroll
    for (int o = 0; o < TK; ++o) {
        float bv = v; int bc = c;
        #pragma unroll
        for (int off = 32; off; off >>= 1) {
            float ov = __shfl_xor(bv, off);
            int   oc = __shfl_xor(bc, off);
            bool take = (ov > bv) || (ov == bv && oc < bc);
            bv = take ? ov : bv;
            bc = take ? oc : bc;
        }
        tvv[o] = bv; ti[o] = bc;
        if (c == bc) v = NEG_BIG;
    }

    float p[TK]; float Z = 0.f;
    #pragma unroll
    for (int j = 0; j < TK; ++j) { p[j] = expf(tvv[j] - tvv[0]); Z += p[j]; }
    const float invZ = 1.f / Z;
    #pragma unroll
    for (int j = 0; j < TK; ++j) p[j] *= invZ;

    float4 eh = *(const float4*)(ehr + lane * 4);

    float4 nb[TK]; float kw[TK];
    #pragma unroll
    for (int k = 0; k < TK; ++k) {
        float4 n = *(const float4*)(e_t + (size_t)ti[k] * 256 + lane * 4);
        nb[k] = n;
        const float pk = p[k], qk = 1.f - p[k];
        float4 gt;
        gt.x = tanhf(eh.x + (pk * n.x + qk * eh.x));
        gt.y = tanhf(eh.y + (pk * n.y + qk * eh.y));
        gt.z = tanhf(eh.z + (pk * n.z + qk * eh.z));
        gt.w = tanhf(eh.w + (pk * n.w + qk * eh.w));
        float d = n.x*gt.x + n.y*gt.y + n.z*gt.z + n.w*gt.w;
        #pragma unroll
        for (int off = 32; off; off >>= 1) d += __shfl_xor(d, off);
        kw[k] = d;
    }

    float km = kw[0];
    #pragma unroll
    for (int k = 1; k < TK; ++k) km = fmaxf(km, kw[k]);
    float kz = 0.f; float kp[TK];
    #pragma unroll
    for (int k = 0; k < TK; ++k) { kp[k] = expf(kw[k] - km); kz += kp[k]; }
    const float invKZ = 1.f / kz;

    float4 acc = make_float4(0.f, 0.f, 0.f, 0.f);
    #pragma unroll
    for (int k = 0; k < TK; ++k) {
        acc.x += kp[k] * nb[k].x;
        acc.y += kp[k] * nb[k].y;
        acc.z += kp[k] * nb[k].z;
        acc.w += kp[k] * nb[k].w;
    }
    acc.x *= invKZ; acc.y *= invKZ; acc.z *= invKZ; acc.w *= invKZ;
    *(float4*)(e_Nh + (size_t)row * 256 + lane * 4) = acc;
}

// ---------------------------------------------------------------------------
extern "C" void kernel_launch(void* const* d_in, const int* in_sizes, int n_in,
                              void* d_out, int out_size, void* d_ws, size_t ws_size,
                              hipStream_t stream)
{
    (void)in_sizes; (void)n_in; (void)out_size; (void)ws_size;
    const float* x     = (const float*)d_in[0];
    const float* wsi_w = (const float*)d_in[1];
    const float* wsi_b = (const float*)d_in[2];
    const float* wh_w  = (const float*)d_in[3];
    const float* wh_b  = (const float*)d_in[4];
    const float* wt_w  = (const float*)d_in[5];
    const float* wt_b  = (const float*)d_in[6];
    const float* w1_w  = (const float*)d_in[7];
    const float* w1_b  = (const float*)d_in[8];
    const float* w2_w  = (const float*)d_in[9];
    const float* w2_b  = (const float*)d_in[10];
    float* out = (float*)d_out;
    float* ws  = (float*)d_ws;

    const int M = NROW;
    const size_t ND = (size_t)M * 256;            // 3,145,728

    float* h    = ws;                             // reused as e_Nh
    float* e_h  = ws + ND;
    float* e_t  = ws + 2*ND;
    _Float16* ehh = (_Float16*)(ws + 3*ND);       // ND halfs
    _Float16* eth = (_Float16*)(ws + 3*ND + ND/2);
    size_t o = 4*ND;
    float* tau12 = ws + o;                        o += (size_t)NCH*NROW*TK;
    float* tau = ws + o;                          o += NROW;
    unsigned int* cnt = (unsigned int*)(ws + o);  o += NROW;
    int* cand = (int*)(ws + o);                   o += (size_t)NROW*64;
    _Float16* hp = (_Float16*)(ws + o);
    _Float16* wsiH = hp;                 // 1024*256 halfs
    _Float16* wsiL = hp + 262144;
    _Float16* whH  = hp + 524288;        // 256*256 each below
    _Float16* whL  = hp + 524288 + 65536;
    _Float16* wtH  = hp + 524288 + 2*65536;
    _Float16* wtL  = hp + 524288 + 3*65536;
    _Float16* w1H  = hp + 524288 + 4*65536;
    _Float16* w1L  = hp + 524288 + 5*65536;
    _Float16* w2H  = hp + 524288 + 6*65536;
    _Float16* w2L  = hp + 524288 + 7*65536;
    float* e_Nh = h;

    // pack weights into fragment layout
    wpack<<<128, 256, 0, stream>>>(wsi_w, wsiH, wsiL, 256, 32);
    wpack<<<32, 256, 0, stream>>>(wh_w, whH, whL, 256, 8);
    wpack<<<32, 256, 0, stream>>>(wt_w, wtH, wtL, 256, 8);
    wpack<<<32, 256, 0, stream>>>(w1_w, w1H, w1L, 256, 8);
    wpack<<<32, 256, 0, stream>>>(w2_w, w2H, w2L, 256, 8);

    // K1: h = relu(x @ wsi + b)
    gemm_mfma<true><<<dim3(4, M/64), 256, 0, stream>>>(
        x, wsiH, wsiL, wsi_b, h, 1024);
    // K2 fused: e_h = h@wh + bh ; e_t = h@wt + bt
    gemm_dual<0><<<dim3(4, M/64), 256, 0, stream>>>(
        h, nullptr, whH, whL, wtH, wtL, wh_b, wt_b, e_h, e_t);
    // pack activations (hi only)
    pack_hi<<<1536, 256, 0, stream>>>(e_h, ehh, 0.0625f);
    pack_hi<<<1536, 256, 0, stream>>>(e_t, eth, 1.0f);
    // S1 / B1 / S2 / S3
    s1_gmax<<<NCH*96, 256, 0, stream>>>(ehh, eth, tau12);
    b1_tau<<<M/256, 256, 0, stream>>>(tau12, tau);
    hipMemsetAsync(cnt, 0, (size_t)M*sizeof(unsigned int), stream);
    s2_collect<<<NCH*96, 256, 0, stream>>>(ehh, eth, tau, cnt, cand);
    s3_tail<<<M/4, 256, 0, stream>>>(e_h, e_t, cnt, cand, e_Nh);
    // K5 fused: out = relu((e_h+e_Nh)@w1+b1) + relu((e_h*e_Nh)@w2+b2)
    gemm_dual<1><<<dim3(4, M/64), 256, 0, stream>>>(
        e_h, e_Nh, w1H, w1L, w2H, w2L, w1_b, w2_b, out, nullptr);
}

// Round 8
// 394.342 us; speedup vs baseline: 2.1768x; 1.0471x over previous
//
#include <hip/hip_runtime.h>
#include <hip/hip_bf16.h>
#include <cmath>

#define TK 12
#define NROW 12288
#define NEG_BIG (-3.0e38f)
#define MFMA16(a,b,c) __builtin_amdgcn_mfma_f32_16x16x32_f16(a,b,c,0,0,0)

// 8 column chunks of 1536 cols = 96 tiles of 16 cols; 48 32-col groups/chunk
#define NCH 8
#define CTILES 96
#define NGRP 48

typedef _Float16 f16x8 __attribute__((ext_vector_type(8)));
typedef _Float16 f16x4 __attribute__((ext_vector_type(4)));
typedef float    f32x4 __attribute__((ext_vector_type(4)));

typedef __attribute__((address_space(1))) const void gvoid_t;
typedef __attribute__((address_space(3))) void lvoid_t;
__device__ __forceinline__ void gload_lds16(const void* g, void* l) {
    __builtin_amdgcn_global_load_lds((gvoid_t*)g, (lvoid_t*)l, 16, 0, 0);
}

// ---------------------------------------------------------------------------
// wpack: W [K][N] f32 -> A-operand fragments of W^T, hi/lo f16. (K1 weights)
// P[cg][s][l][j] = W[s*32 + 8*(l>>4) + j][cg*16 + (l&15)], linear idx = tid*8.
// ---------------------------------------------------------------------------
__global__ __launch_bounds__(256) void wpack(
    const float* __restrict__ W, _Float16* __restrict__ hi,
    _Float16* __restrict__ lo, int N, int nkt)
{
    const int tid = blockIdx.x * 256 + threadIdx.x;
    const int l = tid & 63;
    const int s = (tid >> 6) % nkt;
    const int cg = tid / (nkt * 64);
    const int krow = s * 32 + 8 * (l >> 4);
    const int col = cg * 16 + (l & 15);
    f16x8 H, L;
    #pragma unroll
    for (int j = 0; j < 8; ++j) {
        float w = W[(size_t)(krow + j) * N + col];
        _Float16 h = (_Float16)w;
        H[j] = h;
        L[j] = (_Float16)(w - (float)h);
    }
    *(f16x8*)(hi + (size_t)tid * 8) = H;
    *(f16x8*)(lo + (size_t)tid * 8) = L;
}

// batched wpack for the four 256x256 weights (wh, wt, w1, w2)
__global__ __launch_bounds__(256) void wpack4(
    const float* __restrict__ W0, const float* __restrict__ W1,
    const float* __restrict__ W2, const float* __restrict__ W3,
    _Float16* __restrict__ base)
{
    const int m = blockIdx.y;
    const float* W = (m == 0) ? W0 : (m == 1) ? W1 : (m == 2) ? W2 : W3;
    _Float16* hi = base + (size_t)m * 131072;
    _Float16* lo = hi + 65536;
    const int tid = blockIdx.x * 256 + threadIdx.x;   // 0..8191
    const int l = tid & 63;
    const int s = (tid >> 6) & 7;
    const int cg = tid >> 9;
    const int krow = s * 32 + 8 * (l >> 4);
    const int col = cg * 16 + (l & 15);
    f16x8 H, L;
    #pragma unroll
    for (int j = 0; j < 8; ++j) {
        float w = W[(size_t)(krow + j) * 256 + col];
        _Float16 h = (_Float16)w;
        H[j] = h;
        L[j] = (_Float16)(w - (float)h);
    }
    *(f16x8*)(hi + (size_t)tid * 8) = H;
    *(f16x8*)(lo + (size_t)tid * 8) = L;
}

// ---------------------------------------------------------------------------
// gemm_mfma (K1): C = relu?( A @ W + bias ). Grid (4,192) = 768 blocks.
// Block = 64 rows x 64 cols; wave owns 1 colgroup x 64 rows.
// ---------------------------------------------------------------------------
template<bool RELU>
__global__ __launch_bounds__(256) void gemm_mfma(
    const float* __restrict__ A1,
    const _Float16* __restrict__ Wh, const _Float16* __restrict__ Wl,
    const float* __restrict__ bias, float* __restrict__ C, int K)
{
    __shared__ _Float16 aH[2048], aL[2048];
    __shared__ _Float16 wH[2048], wL[2048];
    const int tid = threadIdx.x, lane = tid & 63, wave = tid >> 6;
    const int rb = blockIdx.y * 64;
    const int cbg = blockIdx.x * 4;
    const int nkt = K >> 5;

    const int arow = rb + wave * 16 + (lane & 15);
    const int acol0 = 8 * (lane >> 4);
    const float* a1p = A1 + (size_t)arow * K + acol0;

    f32x4 acc[4];
    #pragma unroll
    for (int rg = 0; rg < 4; ++rg) acc[rg] = (f32x4){0.f,0.f,0.f,0.f};

    for (int kt = 0; kt < nkt; ++kt) {
        __syncthreads();
        {
            float v[8];
            *(float4*)v       = *(const float4*)(a1p + kt*32);
            *(float4*)(v + 4) = *(const float4*)(a1p + kt*32 + 4);
            f16x8 H, L;
            #pragma unroll
            for (int j = 0; j < 8; ++j) {
                _Float16 h = (_Float16)v[j];
                H[j] = h;
                L[j] = (_Float16)(v[j] - (float)h);
            }
            *(f16x8*)&aH[tid*8] = H;
            *(f16x8*)&aL[tid*8] = L;
        }
        {
            const size_t goff = ((size_t)(cbg + (tid >> 6)) * nkt + kt) * 512 + (tid & 63)*8;
            *(f16x8*)&wH[tid*8] = *(const f16x8*)(Wh + goff);
            *(f16x8*)&wL[tid*8] = *(const f16x8*)(Wl + goff);
        }
        __syncthreads();
        f16x8 wh = *(const f16x8*)&wH[(wave*64 + lane)*8];
        f16x8 wl = *(const f16x8*)&wL[(wave*64 + lane)*8];
        #pragma unroll
        for (int rg = 0; rg < 4; ++rg) {
            f16x8 ah = *(const f16x8*)&aH[(rg*64 + lane)*8];
            f16x8 al = *(const f16x8*)&aL[(rg*64 + lane)*8];
            acc[rg] = MFMA16(wh, ah, acc[rg]);
            acc[rg] = MFMA16(wl, ah, acc[rg]);
            acc[rg] = MFMA16(wh, al, acc[rg]);
        }
    }
    const int col = (cbg + wave)*16 + 4*(lane >> 4);
    float4 b4 = *(const float4*)(bias + col);
    #pragma unroll
    for (int rg = 0; rg < 4; ++rg) {
        const int row = rb + rg*16 + (lane & 15);
        float4 o;
        o.x = acc[rg][0] + b4.x; o.y = acc[rg][1] + b4.y;
        o.z = acc[rg][2] + b4.z; o.w = acc[rg][3] + b4.w;
        if (RELU) {
            o.x = fmaxf(o.x, 0.f); o.y = fmaxf(o.y, 0.f);
            o.z = fmaxf(o.z, 0.f); o.w = fmaxf(o.w, 0.f);
        }
        *(float4*)(C + (size_t)row*256 + col) = o;
    }
}

// ---------------------------------------------------------------------------
// gemm_dual: K=N=256 fused pair. Grid (4,192) = 768 blocks; wave owns 1 cg.
//  DMODE 0: C1 = A1@W1+b1 ; C2 = A1@W2+b2 ; ALSO packs C1*0.0625 -> P1 (f16
//           fragment layout) and C2 -> P2 in the epilogue.
//  DMODE 1: C1 = relu((A1+A2)@W1+b1) + relu((A1*A2)@W2+b2)
// ---------------------------------------------------------------------------
template<int DMODE>
__global__ __launch_bounds__(256) void gemm_dual(
    const float* __restrict__ A1, const float* __restrict__ A2,
    const _Float16* __restrict__ W1h, const _Float16* __restrict__ W1l,
    const _Float16* __restrict__ W2h, const _Float16* __restrict__ W2l,
    const float* __restrict__ bias1, const float* __restrict__ bias2,
    float* __restrict__ C1, float* __restrict__ C2,
    _Float16* __restrict__ P1, _Float16* __restrict__ P2)
{
    __shared__ _Float16 aH[2][2048], aL[2][2048];
    __shared__ _Float16 wH[2][2048], wL[2][2048];
    const int tid = threadIdx.x, lane = tid & 63, wave = tid >> 6;
    const int rb = blockIdx.y * 64;
    const int cbg = blockIdx.x * 4;

    const int arow = rb + wave * 16 + (lane & 15);
    const int acol0 = 8 * (lane >> 4);
    const float* a1p = A1 + (size_t)arow * 256 + acol0;
    const float* a2p = (DMODE == 1) ? (A2 + (size_t)arow * 256 + acol0) : nullptr;

    f32x4 acc1[4], acc2[4];
    #pragma unroll
    for (int rg = 0; rg < 4; ++rg) {
        acc1[rg] = (f32x4){0.f,0.f,0.f,0.f};
        acc2[rg] = (f32x4){0.f,0.f,0.f,0.f};
    }

    for (int kt = 0; kt < 8; ++kt) {
        __syncthreads();
        {
            float v[8];
            *(float4*)v       = *(const float4*)(a1p + kt*32);
            *(float4*)(v + 4) = *(const float4*)(a1p + kt*32 + 4);
            if (DMODE == 0) {
                f16x8 H, L;
                #pragma unroll
                for (int j = 0; j < 8; ++j) {
                    _Float16 h = (_Float16)v[j];
                    H[j] = h;
                    L[j] = (_Float16)(v[j] - (float)h);
                }
                *(f16x8*)&aH[0][tid*8] = H;
                *(f16x8*)&aL[0][tid*8] = L;
            } else {
                float b[8];
                *(float4*)b       = *(const float4*)(a2p + kt*32);
                *(float4*)(b + 4) = *(const float4*)(a2p + kt*32 + 4);
                f16x8 Hs, Ls, Hm, Lm;
                #pragma unroll
                for (int j = 0; j < 8; ++j) {
                    float s = v[j] + b[j];
                    float m = v[j] * b[j];
                    _Float16 hs = (_Float16)s;
                    _Float16 hm = (_Float16)m;
                    Hs[j] = hs; Ls[j] = (_Float16)(s - (float)hs);
                    Hm[j] = hm; Lm[j] = (_Float16)(m - (float)hm);
                }
                *(f16x8*)&aH[0][tid*8] = Hs;
                *(f16x8*)&aL[0][tid*8] = Ls;
                *(f16x8*)&aH[1][tid*8] = Hm;
                *(f16x8*)&aL[1][tid*8] = Lm;
            }
        }
        {
            const size_t goff = ((size_t)(cbg + (tid >> 6)) * 8 + kt) * 512 + (tid & 63)*8;
            *(f16x8*)&wH[0][tid*8] = *(const f16x8*)(W1h + goff);
            *(f16x8*)&wL[0][tid*8] = *(const f16x8*)(W1l + goff);
            *(f16x8*)&wH[1][tid*8] = *(const f16x8*)(W2h + goff);
            *(f16x8*)&wL[1][tid*8] = *(const f16x8*)(W2l + goff);
        }
        __syncthreads();
        f16x8 w1h = *(const f16x8*)&wH[0][(wave*64 + lane)*8];
        f16x8 w1l = *(const f16x8*)&wL[0][(wave*64 + lane)*8];
        f16x8 w2h = *(const f16x8*)&wH[1][(wave*64 + lane)*8];
        f16x8 w2l = *(const f16x8*)&wL[1][(wave*64 + lane)*8];
        #pragma unroll
        for (int rg = 0; rg < 4; ++rg) {
            f16x8 ah0 = *(const f16x8*)&aH[0][(rg*64 + lane)*8];
            f16x8 al0 = *(const f16x8*)&aL[0][(rg*64 + lane)*8];
            acc1[rg] = MFMA16(w1h, ah0, acc1[rg]);
            acc1[rg] = MFMA16(w1l, ah0, acc1[rg]);
            acc1[rg] = MFMA16(w1h, al0, acc1[rg]);
            f16x8 ah1 = (DMODE == 1) ? *(const f16x8*)&aH[1][(rg*64 + lane)*8] : ah0;
            f16x8 al1 = (DMODE == 1) ? *(const f16x8*)&aL[1][(rg*64 + lane)*8] : al0;
            acc2[rg] = MFMA16(w2h, ah1, acc2[rg]);
            acc2[rg] = MFMA16(w2l, ah1, acc2[rg]);
            acc2[rg] = MFMA16(w2h, al1, acc2[rg]);
        }
    }
    const int col = (cbg + wave)*16 + 4*(lane >> 4);
    float4 b14 = *(const float4*)(bias1 + col);
    float4 b24 = *(const float4*)(bias2 + col);
    #pragma unroll
    for (int rg = 0; rg < 4; ++rg) {
        const int row = rb + rg*16 + (lane & 15);
        if (DMODE == 0) {
            float4 o1, o2;
            o1.x = acc1[rg][0] + b14.x; o1.y = acc1[rg][1] + b14.y;
            o1.z = acc1[rg][2] + b14.z; o1.w = acc1[rg][3] + b14.w;
            o2.x = acc2[rg][0] + b24.x; o2.y = acc2[rg][1] + b24.y;
            o2.z = acc2[rg][2] + b24.z; o2.w = acc2[rg][3] + b24.w;
            *(float4*)(C1 + (size_t)row*256 + col) = o1;
            *(float4*)(C2 + (size_t)row*256 + col) = o2;
            // fused pack into MFMA fragment layout
            const size_t poff = ((size_t)(row >> 4)*8 + (col >> 5))*512
                              + (((col & 31) >> 3)*16 + (row & 15))*8 + (col & 7);
            f16x4 p1, p2;
            p1[0] = (_Float16)(o1.x * 0.0625f); p1[1] = (_Float16)(o1.y * 0.0625f);
            p1[2] = (_Float16)(o1.z * 0.0625f); p1[3] = (_Float16)(o1.w * 0.0625f);
            p2[0] = (_Float16)o2.x; p2[1] = (_Float16)o2.y;
            p2[2] = (_Float16)o2.z; p2[3] = (_Float16)o2.w;
            *(f16x4*)(P1 + poff) = p1;
            *(f16x4*)(P2 + poff) = p2;
        } else {
            float4 o;
            o.x = fmaxf(acc1[rg][0] + b14.x, 0.f) + fmaxf(acc2[rg][0] + b24.x, 0.f);
            o.y = fmaxf(acc1[rg][1] + b14.y, 0.f) + fmaxf(acc2[rg][1] + b24.y, 0.f);
            o.z = fmaxf(acc1[rg][2] + b14.z, 0.f) + fmaxf(acc2[rg][2] + b24.z, 0.f);
            o.w = fmaxf(acc1[rg][3] + b14.w, 0.f) + fmaxf(acc2[rg][3] + b24.w, 0.f);
            *(float4*)(C1 + (size_t)row*256 + col) = o;
        }
    }
}

// ---------------------------------------------------------------------------
// S1: per-(row, 32-col-group) maxima, 1-term f16, + per-chunk sorted top-12
// of group maxima. Grid = 8 chunks x 96 rowblocks = 768 blocks (3/CU).
// Block = 4 waves x 32 rows. __launch_bounds__(256,2): 256-VGPR budget so the
// 64-VGPR bh set stays resident (round-7 lesson: default budget spilled it).
// ---------------------------------------------------------------------------
__global__ __launch_bounds__(256, 2) void s1_gmax(
    const _Float16* __restrict__ ehh, const _Float16* __restrict__ eth,
    float* __restrict__ tau12)
{
    __shared__ _Float16 abuf[3][4096];          // 3 x 8KB tiles
    __shared__ unsigned short gml[NGRP * 128];  // 12KB
    const int tid = threadIdx.x, lane = tid & 63, wave = tid >> 6;
    const int chunk = blockIdx.x & (NCH-1);     // == XCD id (L2 affinity)
    const int rblk = blockIdx.x >> 3;           // 0..95
    const int rg0 = rblk * 8 + wave * 2;

    f16x8 bh[2][8];
    #pragma unroll
    for (int rs = 0; rs < 2; ++rs) {
        const _Float16* p = ehh + (size_t)(rg0 + rs)*4096 + lane*8;
        #pragma unroll
        for (int s = 0; s < 8; ++s) bh[rs][s] = *(const f16x8*)(p + s*512);
    }
    #pragma unroll
    for (int rs = 0; rs < 2; ++rs)
        #pragma unroll
        for (int s = 0; s < 8; ++s)
            asm volatile("" : "+v"(bh[rs][s]));

    const _Float16* gsrc = eth + (size_t)chunk * CTILES * 4096;
    #pragma unroll
    for (int i = 0; i < 2; ++i)
        gload_lds16(gsrc + (wave*2+i)*512 + lane*8, &abuf[0][(wave*2+i)*512]);
    #pragma unroll
    for (int i = 0; i < 2; ++i)
        gload_lds16(gsrc + 4096 + (wave*2+i)*512 + lane*8, &abuf[1][(wave*2+i)*512]);
    asm volatile("s_waitcnt vmcnt(2) lgkmcnt(0)" ::: "memory");
    __builtin_amdgcn_s_barrier();
    asm volatile("" ::: "memory");

    float gm[2] = {NEG_BIG, NEG_BIG};
    int cur = 0;
    for (int t = 0; t < CTILES; ++t) {
        int nx2 = cur - 1; if (nx2 < 0) nx2 = 2;
        if (t + 2 < CTILES) {
            #pragma unroll
            for (int i = 0; i < 2; ++i)
                gload_lds16(gsrc + (size_t)(t+2)*4096 + (wave*2+i)*512 + lane*8,
                            &abuf[nx2][(wave*2+i)*512]);
        }
        f32x4 aE[2], aO[2];
        #pragma unroll
        for (int rs = 0; rs < 2; ++rs) {
            aE[rs] = (f32x4){0.f,0.f,0.f,0.f};
            aO[rs] = (f32x4){0.f,0.f,0.f,0.f};
        }
        #pragma unroll
        for (int s = 0; s < 8; ++s) {
            f16x8 ah = *(const f16x8*)&abuf[cur][s*512 + lane*8];
            if (s & 1) {
                #pragma unroll
                for (int rs = 0; rs < 2; ++rs) aO[rs] = MFMA16(ah, bh[rs][s], aO[rs]);
            } else {
                #pragma unroll
                for (int rs = 0; rs < 2; ++rs) aE[rs] = MFMA16(ah, bh[rs][s], aE[rs]);
            }
        }
        #pragma unroll
        for (int rs = 0; rs < 2; ++rs) {
            f32x4 a = aE[rs] + aO[rs];
            float m = fmaxf(fmaxf(a[0],a[1]), fmaxf(a[2],a[3]));
            m = fmaxf(m, __shfl_xor(m, 16));
            m = fmaxf(m, __shfl_xor(m, 32));
            gm[rs] = (t & 1) ? fmaxf(gm[rs], m) : m;
        }
        if ((t & 1) && lane < 16) {
            #pragma unroll
            for (int rs = 0; rs < 2; ++rs) {
                float g = gm[rs];
                unsigned u = (__float_as_uint(g) >> 16) + (g < 0.f ? 1u : 0u);
                gml[(t>>1)*128 + wave*32 + rs*16 + lane] = (unsigned short)u;
            }
        }
        if (t + 2 < CTILES) { asm volatile("s_waitcnt vmcnt(2)" ::: "memory"); }
        else                { asm volatile("s_waitcnt vmcnt(0)" ::: "memory"); }
        __builtin_amdgcn_s_barrier();
        asm volatile("" ::: "memory");
        cur = (cur >= 2) ? 0 : cur + 1;
    }
    asm volatile("s_waitcnt lgkmcnt(0)" ::: "memory");
    __builtin_amdgcn_s_barrier();
    asm volatile("" ::: "memory");
    // per-row sorted top-12 of this chunk's 48 group maxima
    if (tid < 128) {
        float tv[TK];
        #pragma unroll
        for (int j = 0; j < TK; ++j) tv[j] = NEG_BIG;
        for (int g = 0; g < NGRP; ++g) {
            float v = __uint_as_float(((unsigned)gml[g*128 + tid]) << 16);
            #pragma unroll
            for (int j = TK-1; j >= 1; --j)
                tv[j] = __builtin_amdgcn_fmed3f(v, tv[j], tv[j-1]);
            tv[0] = fmaxf(v, tv[0]);
        }
        float* op = tau12 + ((size_t)chunk*NROW + rblk*128 + tid)*TK;
        #pragma unroll
        for (int j = 0; j < TK; ++j) op[j] = tv[j];
    }
}

// ---------------------------------------------------------------------------
// B1: tau[row] = 12th-largest of the union of 8 per-chunk top-12 lists, - margin.
// ---------------------------------------------------------------------------
__global__ __launch_bounds__(256) void b1_tau(
    const float* __restrict__ tau12, float* __restrict__ tau)
{
    const int row = blockIdx.x * 256 + threadIdx.x;
    float tv[TK];
    #pragma unroll
    for (int j = 0; j < TK; ++j) tv[j] = NEG_BIG;
    #pragma unroll 1
    for (int c = 0; c < NCH; ++c) {
        const float* p = tau12 + ((size_t)c*NROW + row)*TK;
        float4 q0 = *(const float4*)p;
        float4 q1 = *(const float4*)(p + 4);
        float4 q2 = *(const float4*)(p + 8);
        float vv[TK] = {q0.x,q0.y,q0.z,q0.w, q1.x,q1.y,q1.z,q1.w, q2.x,q2.y,q2.z,q2.w};
        #pragma unroll
        for (int i = 0; i < TK; ++i) {
            float v = vv[i];
            #pragma unroll
            for (int j = TK-1; j >= 1; --j)
                tv[j] = __builtin_amdgcn_fmed3f(v, tv[j], tv[j-1]);
            tv[0] = fmaxf(v, tv[0]);
        }
    }
    tau[row] = tv[TK-1] - 0.02f;
}

// ---------------------------------------------------------------------------
// S2: 1-term scores; collect columns >= tau[row] into LDS, flush once.
// Same geometry as S1; same register-budget fix.
// ---------------------------------------------------------------------------
#define S2CAP 1024
__global__ __launch_bounds__(256, 2) void s2_collect(
    const _Float16* __restrict__ ehh, const _Float16* __restrict__ eth,
    const float* __restrict__ tau, unsigned int* __restrict__ cnt,
    int* __restrict__ cand)
{
    __shared__ _Float16 abuf[3][4096];
    __shared__ int cmeta[S2CAP];
    __shared__ unsigned int lcnt;
    const int tid = threadIdx.x, lane = tid & 63, wave = tid >> 6;
    const int chunk = blockIdx.x & (NCH-1);
    const int rblk = blockIdx.x >> 3;
    const int rg0 = rblk * 8 + wave * 2;
    if (tid == 0) lcnt = 0;

    f16x8 bh[2][8];
    #pragma unroll
    for (int rs = 0; rs < 2; ++rs) {
        const _Float16* p = ehh + (size_t)(rg0 + rs)*4096 + lane*8;
        #pragma unroll
        for (int s = 0; s < 8; ++s) bh[rs][s] = *(const f16x8*)(p + s*512);
    }
    #pragma unroll
    for (int rs = 0; rs < 2; ++rs)
        #pragma unroll
        for (int s = 0; s < 8; ++s)
            asm volatile("" : "+v"(bh[rs][s]));

    float tvr[2];
    #pragma unroll
    for (int rs = 0; rs < 2; ++rs)
        tvr[rs] = tau[rblk*128 + wave*32 + rs*16 + (lane & 15)];

    const _Float16* gsrc = eth + (size_t)chunk * CTILES * 4096;
    #pragma unroll
    for (int i = 0; i < 2; ++i)
        gload_lds16(gsrc + (wave*2+i)*512 + lane*8, &abuf[0][(wave*2+i)*512]);
    #pragma unroll
    for (int i = 0; i < 2; ++i)
        gload_lds16(gsrc + 4096 + (wave*2+i)*512 + lane*8, &abuf[1][(wave*2+i)*512]);
    asm volatile("s_waitcnt vmcnt(2) lgkmcnt(0)" ::: "memory");
    __builtin_amdgcn_s_barrier();
    asm volatile("" ::: "memory");

    int cur = 0;
    for (int t = 0; t < CTILES; ++t) {
        int nx2 = cur - 1; if (nx2 < 0) nx2 = 2;
        if (t + 2 < CTILES) {
            #pragma unroll
            for (int i = 0; i < 2; ++i)
                gload_lds16(gsrc + (size_t)(t+2)*4096 + (wave*2+i)*512 + lane*8,
                            &abuf[nx2][(wave*2+i)*512]);
        }
        f32x4 aE[2], aO[2];
        #pragma unroll
        for (int rs = 0; rs < 2; ++rs) {
            aE[rs] = (f32x4){0.f,0.f,0.f,0.f};
            aO[rs] = (f32x4){0.f,0.f,0.f,0.f};
        }
        #pragma unroll
        for (int s = 0; s < 8; ++s) {
            f16x8 ah = *(const f16x8*)&abuf[cur][s*512 + lane*8];
            if (s & 1) {
                #pragma unroll
                for (int rs = 0; rs < 2; ++rs) aO[rs] = MFMA16(ah, bh[rs][s], aO[rs]);
            } else {
                #pragma unroll
                for (int rs = 0; rs < 2; ++rs) aE[rs] = MFMA16(ah, bh[rs][s], aE[rs]);
            }
        }
        const int cb = (chunk*CTILES + t)*16 + 4*(lane >> 4);
        #pragma unroll
        for (int rs = 0; rs < 2; ++rs) {
            f32x4 a = aE[rs] + aO[rs];
            float m = fmaxf(fmaxf(a[0],a[1]), fmaxf(a[2],a[3]));
            if (__any(m >= tvr[rs])) {
                const int lrow = wave*32 + rs*16 + (lane & 15);
                #pragma unroll
                for (int e = 0; e < 4; ++e) {
                    if (a[e] >= tvr[rs]) {
                        unsigned p = atomicAdd(&lcnt, 1u);
                        if (p < S2CAP) cmeta[p] = (cb + e) | (lrow << 16);
                    }
                }
            }
        }
        if (t + 2 < CTILES) { asm volatile("s_waitcnt vmcnt(2)" ::: "memory"); }
        else                { asm volatile("s_waitcnt vmcnt(0)" ::: "memory"); }
        __builtin_amdgcn_s_barrier();
        asm volatile("" ::: "memory");
        cur = (cur >= 2) ? 0 : cur + 1;
    }
    asm volatile("s_waitcnt lgkmcnt(0)" ::: "memory");
    __builtin_amdgcn_s_barrier();
    asm volatile("" ::: "memory");
    const int row0 = rblk * 128;
    const unsigned n = (lcnt < (unsigned)S2CAP) ? lcnt : (unsigned)S2CAP;
    for (unsigned i = tid; i < n; i += 256) {
        const int m = cmeta[i];
        const int row = row0 + (m >> 16);
        unsigned p = atomicAdd(&cnt[row], 1u);
        if (p < 64) cand[(size_t)row*64 + p] = m & 0xffff;
    }
}

// ---------------------------------------------------------------------------
// S3: exact f32 rescoring of candidates, top-12 (val desc, col asc),
// softmax / gather / tanh-gate / ka-softmax / e_Nh. One wave per row.
// ---------------------------------------------------------------------------
__global__ __launch_bounds__(256) void s3_tail(
    const float* __restrict__ e_h, const float* __restrict__ e_t,
    const unsigned int* __restrict__ cnt, const int* __restrict__ cand,
    float* __restrict__ e_Nh)
{
    const int lane = threadIdx.x & 63;
    const int wave = threadIdx.x >> 6;
    const int row  = blockIdx.x * 4 + wave;

    const unsigned cn = min(cnt[row], 64u);
    const bool act = lane < (int)cn;
    int colc = act ? cand[(size_t)row*64 + lane] : 0x7fffffff;

    const float* ehr = e_h + (size_t)row * 256;
    const float* etr = e_t + (size_t)(act ? colc : 0) * 256;
    float s = 0.f;
    for (int k = 0; k < 64; ++k) {
        float4 a = *(const float4*)(ehr + k*4);
        float4 b = *(const float4*)(etr + k*4);
        s += a.x*b.x + a.y*b.y + a.z*b.z + a.w*b.w;
    }
    s *= 0.0625f;
    if (!act) s = NEG_BIG;

    float tvv[TK]; int ti[TK];
    float v = s; int c = colc;
    #pragma unroll
    for (int o = 0; o < TK; ++o) {
        float bv = v; int bc = c;
        #pragma unroll
        for (int off = 32; off; off >>= 1) {
            float ov = __shfl_xor(bv, off);
            int   oc = __shfl_xor(bc, off);
            bool take = (ov > bv) || (ov == bv && oc < bc);
            bv = take ? ov : bv;
            bc = take ? oc : bc;
        }
        tvv[o] = bv; ti[o] = bc;
        if (c == bc) v = NEG_BIG;
    }

    float p[TK]; float Z = 0.f;
    #pragma unroll
    for (int j = 0; j < TK; ++j) { p[j] = expf(tvv[j] - tvv[0]); Z += p[j]; }
    const float invZ = 1.f / Z;
    #pragma unroll
    for (int j = 0; j < TK; ++j) p[j] *= invZ;

    float4 eh = *(const float4*)(ehr + lane * 4);

    float4 nb[TK]; float kw[TK];
    #pragma unroll
    for (int k = 0; k < TK; ++k) {
        float4 n = *(const float4*)(e_t + (size_t)ti[k] * 256 + lane * 4);
        nb[k] = n;
        const float pk = p[k], qk = 1.f - p[k];
        float4 gt;
        gt.x = tanhf(eh.x + (pk * n.x + qk * eh.x));
        gt.y = tanhf(eh.y + (pk * n.y + qk * eh.y));
        gt.z = tanhf(eh.z + (pk * n.z + qk * eh.z));
        gt.w = tanhf(eh.w + (pk * n.w + qk * eh.w));
        float d = n.x*gt.x + n.y*gt.y + n.z*gt.z + n.w*gt.w;
        #pragma unroll
        for (int off = 32; off; off >>= 1) d += __shfl_xor(d, off);
        kw[k] = d;
    }

    float km = kw[0];
    #pragma unroll
    for (int k = 1; k < TK; ++k) km = fmaxf(km, kw[k]);
    float kz = 0.f; float kp[TK];
    #pragma unroll
    for (int k = 0; k < TK; ++k) { kp[k] = expf(kw[k] - km); kz += kp[k]; }
    const float invKZ = 1.f / kz;

    float4 acc = make_float4(0.f, 0.f, 0.f, 0.f);
    #pragma unroll
    for (int k = 0; k < TK; ++k) {
        acc.x += kp[k] * nb[k].x;
        acc.y += kp[k] * nb[k].y;
        acc.z += kp[k] * nb[k].z;
        acc.w += kp[k] * nb[k].w;
    }
    acc.x *= invKZ; acc.y *= invKZ; acc.z *= invKZ; acc.w *= invKZ;
    *(float4*)(e_Nh + (size_t)row * 256 + lane * 4) = acc;
}

// ---------------------------------------------------------------------------
extern "C" void kernel_launch(void* const* d_in, const int* in_sizes, int n_in,
                              void* d_out, int out_size, void* d_ws, size_t ws_size,
                              hipStream_t stream)
{
    (void)in_sizes; (void)n_in; (void)out_size; (void)ws_size;
    const float* x     = (const float*)d_in[0];
    const float* wsi_w = (const float*)d_in[1];
    const float* wsi_b = (const float*)d_in[2];
    const float* wh_w  = (const float*)d_in[3];
    const float* wh_b  = (const float*)d_in[4];
    const float* wt_w  = (const float*)d_in[5];
    const float* wt_b  = (const float*)d_in[6];
    const float* w1_w  = (const float*)d_in[7];
    const float* w1_b  = (const float*)d_in[8];
    const float* w2_w  = (const float*)d_in[9];
    const float* w2_b  = (const float*)d_in[10];
    float* out = (float*)d_out;
    float* ws  = (float*)d_ws;

    const int M = NROW;
    const size_t ND = (size_t)M * 256;            // 3,145,728

    float* h    = ws;                             // reused as e_Nh
    float* e_h  = ws + ND;
    float* e_t  = ws + 2*ND;
    _Float16* ehh = (_Float16*)(ws + 3*ND);       // ND halfs
    _Float16* eth = (_Float16*)(ws + 3*ND + ND/2);
    size_t o = 4*ND;
    float* tau12 = ws + o;                        o += (size_t)NCH*NROW*TK;
    float* tau = ws + o;                          o += NROW;
    unsigned int* cnt = (unsigned int*)(ws + o);  o += NROW;
    int* cand = (int*)(ws + o);                   o += (size_t)NROW*64;
    _Float16* hp = (_Float16*)(ws + o);
    _Float16* wsiH = hp;                 // 1024*256 halfs
    _Float16* wsiL = hp + 262144;
    _Float16* w4base = hp + 524288;      // wh{H,L}, wt{H,L}, w1{H,L}, w2{H,L}
    _Float16* whH  = w4base;
    _Float16* whL  = w4base + 65536;
    _Float16* wtH  = w4base + 2*65536;
    _Float16* wtL  = w4base + 3*65536;
    _Float16* w1H  = w4base + 4*65536;
    _Float16* w1L  = w4base + 5*65536;
    _Float16* w2H  = w4base + 6*65536;
    _Float16* w2L  = w4base + 7*65536;
    float* e_Nh = h;

    // pack weights into fragment layout
    wpack<<<128, 256, 0, stream>>>(wsi_w, wsiH, wsiL, 256, 32);
    wpack4<<<dim3(32, 4), 256, 0, stream>>>(wh_w, wt_w, w1_w, w2_w, w4base);

    // K1: h = relu(x @ wsi + b)
    gemm_mfma<true><<<dim3(4, M/64), 256, 0, stream>>>(
        x, wsiH, wsiL, wsi_b, h, 1024);
    // K2 fused: e_h, e_t + packed ehh (x SCALE), eth in epilogue
    gemm_dual<0><<<dim3(4, M/64), 256, 0, stream>>>(
        h, nullptr, whH, whL, wtH, wtL, wh_b, wt_b, e_h, e_t, ehh, eth);
    // S1 / B1 / S2 / S3
    s1_gmax<<<NCH*96, 256, 0, stream>>>(ehh, eth, tau12);
    b1_tau<<<M/256, 256, 0, stream>>>(tau12, tau);
    hipMemsetAsync(cnt, 0, (size_t)M*sizeof(unsigned int), stream);
    s2_collect<<<NCH*96, 256, 0, stream>>>(ehh, eth, tau, cnt, cand);
    s3_tail<<<M/4, 256, 0, stream>>>(e_h, e_t, cnt, cand, e_Nh);
    // K5 fused: out = relu((e_h+e_Nh)@w1+b1) + relu((e_h*e_Nh)@w2+b2)
    gemm_dual<1><<<dim3(4, M/64), 256, 0, stream>>>(
        e_h, e_Nh, w1H, w1L, w2H, w2L, w1_b, w2_b, out, nullptr, nullptr, nullptr);
}

// Round 9
// 360.378 us; speedup vs baseline: 2.3819x; 1.0942x over previous
//
#include <hip/hip_runtime.h>
#include <hip/hip_bf16.h>
#include <cmath>

#define TK 12
#define NROW 12288
#define NEG_BIG (-3.0e38f)
#define MFMA16(a,b,c) __builtin_amdgcn_mfma_f32_16x16x32_f16(a,b,c,0,0,0)

// 8 column chunks of 1536 cols = 96 tiles of 16 cols; 48 2-tile phases/chunk
#define NCH 8
#define CTILES 96
#define NPH 48

typedef _Float16 f16x8 __attribute__((ext_vector_type(8)));
typedef _Float16 f16x4 __attribute__((ext_vector_type(4)));
typedef float    f32x4 __attribute__((ext_vector_type(4)));

typedef __attribute__((address_space(1))) const void gvoid_t;
typedef __attribute__((address_space(3))) void lvoid_t;
__device__ __forceinline__ void gload_lds16(const void* g, void* l) {
    __builtin_amdgcn_global_load_lds((gvoid_t*)g, (lvoid_t*)l, 16, 0, 0);
}

// ---------------------------------------------------------------------------
// wpack: W [K][N] f32 -> A-operand fragments of W^T, hi/lo f16. (K1 weights)
// ---------------------------------------------------------------------------
__global__ __launch_bounds__(256) void wpack(
    const float* __restrict__ W, _Float16* __restrict__ hi,
    _Float16* __restrict__ lo, int N, int nkt)
{
    const int tid = blockIdx.x * 256 + threadIdx.x;
    const int l = tid & 63;
    const int s = (tid >> 6) % nkt;
    const int cg = tid / (nkt * 64);
    const int krow = s * 32 + 8 * (l >> 4);
    const int col = cg * 16 + (l & 15);
    f16x8 H, L;
    #pragma unroll
    for (int j = 0; j < 8; ++j) {
        float w = W[(size_t)(krow + j) * N + col];
        _Float16 h = (_Float16)w;
        H[j] = h;
        L[j] = (_Float16)(w - (float)h);
    }
    *(f16x8*)(hi + (size_t)tid * 8) = H;
    *(f16x8*)(lo + (size_t)tid * 8) = L;
}

// batched wpack for the four 256x256 weights (wh, wt, w1, w2)
__global__ __launch_bounds__(256) void wpack4(
    const float* __restrict__ W0, const float* __restrict__ W1,
    const float* __restrict__ W2, const float* __restrict__ W3,
    _Float16* __restrict__ base)
{
    const int m = blockIdx.y;
    const float* W = (m == 0) ? W0 : (m == 1) ? W1 : (m == 2) ? W2 : W3;
    _Float16* hi = base + (size_t)m * 131072;
    _Float16* lo = hi + 65536;
    const int tid = blockIdx.x * 256 + threadIdx.x;   // 0..8191
    const int l = tid & 63;
    const int s = (tid >> 6) & 7;
    const int cg = tid >> 9;
    const int krow = s * 32 + 8 * (l >> 4);
    const int col = cg * 16 + (l & 15);
    f16x8 H, L;
    #pragma unroll
    for (int j = 0; j < 8; ++j) {
        float w = W[(size_t)(krow + j) * 256 + col];
        _Float16 h = (_Float16)w;
        H[j] = h;
        L[j] = (_Float16)(w - (float)h);
    }
    *(f16x8*)(hi + (size_t)tid * 8) = H;
    *(f16x8*)(lo + (size_t)tid * 8) = L;
}

// ---------------------------------------------------------------------------
// gemm_mfma (K1): C = relu?( A @ W + bias ). Grid (4,192) = 768 blocks.
// Register-prefetched staging (issue kt+1 loads under kt compute).
// ---------------------------------------------------------------------------
template<bool RELU>
__global__ __launch_bounds__(256) void gemm_mfma(
    const float* __restrict__ A1,
    const _Float16* __restrict__ Wh, const _Float16* __restrict__ Wl,
    const float* __restrict__ bias, float* __restrict__ C, int K)
{
    __shared__ _Float16 aH[2048], aL[2048];
    __shared__ _Float16 wH[2048], wL[2048];
    const int tid = threadIdx.x, lane = tid & 63, wave = tid >> 6;
    const int rb = blockIdx.y * 64;
    const int cbg = blockIdx.x * 4;
    const int nkt = K >> 5;

    const int arow = rb + wave * 16 + (lane & 15);
    const int acol0 = 8 * (lane >> 4);
    const float* a1p = A1 + (size_t)arow * K + acol0;
    const size_t wbase = ((size_t)(cbg + wave) * nkt) * 512 + lane * 8;

    f32x4 acc[4];
    #pragma unroll
    for (int rg = 0; rg < 4; ++rg) acc[rg] = (f32x4){0.f,0.f,0.f,0.f};

    // prefetch kt=0
    float4 pa0 = *(const float4*)(a1p);
    float4 pa1 = *(const float4*)(a1p + 4);
    f16x8 pwh = *(const f16x8*)(Wh + wbase);
    f16x8 pwl = *(const f16x8*)(Wl + wbase);

    for (int kt = 0; kt < nkt; ++kt) {
        __syncthreads();
        {
            float v[8] = {pa0.x, pa0.y, pa0.z, pa0.w, pa1.x, pa1.y, pa1.z, pa1.w};
            f16x8 H, L;
            #pragma unroll
            for (int j = 0; j < 8; ++j) {
                _Float16 h = (_Float16)v[j];
                H[j] = h;
                L[j] = (_Float16)(v[j] - (float)h);
            }
            *(f16x8*)&aH[tid*8] = H;
            *(f16x8*)&aL[tid*8] = L;
            *(f16x8*)&wH[tid*8] = pwh;
            *(f16x8*)&wL[tid*8] = pwl;
        }
        __syncthreads();
        if (kt + 1 < nkt) {
            pa0 = *(const float4*)(a1p + (kt+1)*32);
            pa1 = *(const float4*)(a1p + (kt+1)*32 + 4);
            pwh = *(const f16x8*)(Wh + wbase + (size_t)(kt+1)*512);
            pwl = *(const f16x8*)(Wl + wbase + (size_t)(kt+1)*512);
        }
        f16x8 wh = *(const f16x8*)&wH[(wave*64 + lane)*8];
        f16x8 wl = *(const f16x8*)&wL[(wave*64 + lane)*8];
        #pragma unroll
        for (int rg = 0; rg < 4; ++rg) {
            f16x8 ah = *(const f16x8*)&aH[(rg*64 + lane)*8];
            f16x8 al = *(const f16x8*)&aL[(rg*64 + lane)*8];
            acc[rg] = MFMA16(wh, ah, acc[rg]);
            acc[rg] = MFMA16(wl, ah, acc[rg]);
            acc[rg] = MFMA16(wh, al, acc[rg]);
        }
    }
    const int col = (cbg + wave)*16 + 4*(lane >> 4);
    float4 b4 = *(const float4*)(bias + col);
    #pragma unroll
    for (int rg = 0; rg < 4; ++rg) {
        const int row = rb + rg*16 + (lane & 15);
        float4 o;
        o.x = acc[rg][0] + b4.x; o.y = acc[rg][1] + b4.y;
        o.z = acc[rg][2] + b4.z; o.w = acc[rg][3] + b4.w;
        if (RELU) {
            o.x = fmaxf(o.x, 0.f); o.y = fmaxf(o.y, 0.f);
            o.z = fmaxf(o.z, 0.f); o.w = fmaxf(o.w, 0.f);
        }
        *(float4*)(C + (size_t)row*256 + col) = o;
    }
}

// ---------------------------------------------------------------------------
// gemm_dual: K=N=256 fused pair, register-prefetched staging.
//  DMODE 0: C1 = A1@W1+b1 ; C2 = A1@W2+b2 ; packs C1*SCALE->P1, C2->P2.
//  DMODE 1: C1 = relu((A1+A2)@W1+b1) + relu((A1*A2)@W2+b2)
// ---------------------------------------------------------------------------
template<int DMODE>
__global__ __launch_bounds__(256) void gemm_dual(
    const float* __restrict__ A1, const float* __restrict__ A2,
    const _Float16* __restrict__ W1h, const _Float16* __restrict__ W1l,
    const _Float16* __restrict__ W2h, const _Float16* __restrict__ W2l,
    const float* __restrict__ bias1, const float* __restrict__ bias2,
    float* __restrict__ C1, float* __restrict__ C2,
    _Float16* __restrict__ P1, _Float16* __restrict__ P2)
{
    __shared__ _Float16 aH[2][2048], aL[2][2048];
    __shared__ _Float16 wH[2][2048], wL[2][2048];
    const int tid = threadIdx.x, lane = tid & 63, wave = tid >> 6;
    const int rb = blockIdx.y * 64;
    const int cbg = blockIdx.x * 4;

    const int arow = rb + wave * 16 + (lane & 15);
    const int acol0 = 8 * (lane >> 4);
    const float* a1p = A1 + (size_t)arow * 256 + acol0;
    const float* a2p = (DMODE == 1) ? (A2 + (size_t)arow * 256 + acol0) : nullptr;
    const size_t wbase = ((size_t)(cbg + wave) * 8) * 512 + lane * 8;

    f32x4 acc1[4], acc2[4];
    #pragma unroll
    for (int rg = 0; rg < 4; ++rg) {
        acc1[rg] = (f32x4){0.f,0.f,0.f,0.f};
        acc2[rg] = (f32x4){0.f,0.f,0.f,0.f};
    }

    float4 pa0 = *(const float4*)(a1p);
    float4 pa1 = *(const float4*)(a1p + 4);
    float4 pb0, pb1;
    if (DMODE == 1) { pb0 = *(const float4*)(a2p); pb1 = *(const float4*)(a2p + 4); }
    f16x8 pw1h = *(const f16x8*)(W1h + wbase);
    f16x8 pw1l = *(const f16x8*)(W1l + wbase);
    f16x8 pw2h = *(const f16x8*)(W2h + wbase);
    f16x8 pw2l = *(const f16x8*)(W2l + wbase);

    for (int kt = 0; kt < 8; ++kt) {
        __syncthreads();
        {
            float v[8] = {pa0.x, pa0.y, pa0.z, pa0.w, pa1.x, pa1.y, pa1.z, pa1.w};
            if (DMODE == 0) {
                f16x8 H, L;
                #pragma unroll
                for (int j = 0; j < 8; ++j) {
                    _Float16 h = (_Float16)v[j];
                    H[j] = h;
                    L[j] = (_Float16)(v[j] - (float)h);
                }
                *(f16x8*)&aH[0][tid*8] = H;
                *(f16x8*)&aL[0][tid*8] = L;
            } else {
                float b[8] = {pb0.x, pb0.y, pb0.z, pb0.w, pb1.x, pb1.y, pb1.z, pb1.w};
                f16x8 Hs, Ls, Hm, Lm;
                #pragma unroll
                for (int j = 0; j < 8; ++j) {
                    float s = v[j] + b[j];
                    float m = v[j] * b[j];
                    _Float16 hs = (_Float16)s;
                    _Float16 hm = (_Float16)m;
                    Hs[j] = hs; Ls[j] = (_Float16)(s - (float)hs);
                    Hm[j] = hm; Lm[j] = (_Float16)(m - (float)hm);
                }
                *(f16x8*)&aH[0][tid*8] = Hs;
                *(f16x8*)&aL[0][tid*8] = Ls;
                *(f16x8*)&aH[1][tid*8] = Hm;
                *(f16x8*)&aL[1][tid*8] = Lm;
            }
            *(f16x8*)&wH[0][tid*8] = pw1h;
            *(f16x8*)&wL[0][tid*8] = pw1l;
            *(f16x8*)&wH[1][tid*8] = pw2h;
            *(f16x8*)&wL[1][tid*8] = pw2l;
        }
        __syncthreads();
        if (kt + 1 < 8) {
            pa0 = *(const float4*)(a1p + (kt+1)*32);
            pa1 = *(const float4*)(a1p + (kt+1)*32 + 4);
            if (DMODE == 1) {
                pb0 = *(const float4*)(a2p + (kt+1)*32);
                pb1 = *(const float4*)(a2p + (kt+1)*32 + 4);
            }
            pw1h = *(const f16x8*)(W1h + wbase + (size_t)(kt+1)*512);
            pw1l = *(const f16x8*)(W1l + wbase + (size_t)(kt+1)*512);
            pw2h = *(const f16x8*)(W2h + wbase + (size_t)(kt+1)*512);
            pw2l = *(const f16x8*)(W2l + wbase + (size_t)(kt+1)*512);
        }
        f16x8 w1h = *(const f16x8*)&wH[0][(wave*64 + lane)*8];
        f16x8 w1l = *(const f16x8*)&wL[0][(wave*64 + lane)*8];
        f16x8 w2h = *(const f16x8*)&wH[1][(wave*64 + lane)*8];
        f16x8 w2l = *(const f16x8*)&wL[1][(wave*64 + lane)*8];
        #pragma unroll
        for (int rg = 0; rg < 4; ++rg) {
            f16x8 ah0 = *(const f16x8*)&aH[0][(rg*64 + lane)*8];
            f16x8 al0 = *(const f16x8*)&aL[0][(rg*64 + lane)*8];
            acc1[rg] = MFMA16(w1h, ah0, acc1[rg]);
            acc1[rg] = MFMA16(w1l, ah0, acc1[rg]);
            acc1[rg] = MFMA16(w1h, al0, acc1[rg]);
            f16x8 ah1 = (DMODE == 1) ? *(const f16x8*)&aH[1][(rg*64 + lane)*8] : ah0;
            f16x8 al1 = (DMODE == 1) ? *(const f16x8*)&aL[1][(rg*64 + lane)*8] : al0;
            acc2[rg] = MFMA16(w2h, ah1, acc2[rg]);
            acc2[rg] = MFMA16(w2l, ah1, acc2[rg]);
            acc2[rg] = MFMA16(w2h, al1, acc2[rg]);
        }
    }
    const int col = (cbg + wave)*16 + 4*(lane >> 4);
    float4 b14 = *(const float4*)(bias1 + col);
    float4 b24 = *(const float4*)(bias2 + col);
    #pragma unroll
    for (int rg = 0; rg < 4; ++rg) {
        const int row = rb + rg*16 + (lane & 15);
        if (DMODE == 0) {
            float4 o1, o2;
            o1.x = acc1[rg][0] + b14.x; o1.y = acc1[rg][1] + b14.y;
            o1.z = acc1[rg][2] + b14.z; o1.w = acc1[rg][3] + b14.w;
            o2.x = acc2[rg][0] + b24.x; o2.y = acc2[rg][1] + b24.y;
            o2.z = acc2[rg][2] + b24.z; o2.w = acc2[rg][3] + b24.w;
            *(float4*)(C1 + (size_t)row*256 + col) = o1;
            *(float4*)(C2 + (size_t)row*256 + col) = o2;
            const size_t poff = ((size_t)(row >> 4)*8 + (col >> 5))*512
                              + (((col & 31) >> 3)*16 + (row & 15))*8 + (col & 7);
            f16x4 p1, p2;
            p1[0] = (_Float16)(o1.x * 0.0625f); p1[1] = (_Float16)(o1.y * 0.0625f);
            p1[2] = (_Float16)(o1.z * 0.0625f); p1[3] = (_Float16)(o1.w * 0.0625f);
            p2[0] = (_Float16)o2.x; p2[1] = (_Float16)o2.y;
            p2[2] = (_Float16)o2.z; p2[3] = (_Float16)o2.w;
            *(f16x4*)(P1 + poff) = p1;
            *(f16x4*)(P2 + poff) = p2;
        } else {
            float4 o;
            o.x = fmaxf(acc1[rg][0] + b14.x, 0.f) + fmaxf(acc2[rg][0] + b24.x, 0.f);
            o.y = fmaxf(acc1[rg][1] + b14.y, 0.f) + fmaxf(acc2[rg][1] + b24.y, 0.f);
            o.z = fmaxf(acc1[rg][2] + b14.z, 0.f) + fmaxf(acc2[rg][2] + b24.z, 0.f);
            o.w = fmaxf(acc1[rg][3] + b14.w, 0.f) + fmaxf(acc2[rg][3] + b24.w, 0.f);
            *(float4*)(C1 + (size_t)row*256 + col) = o;
        }
    }
}

// ---------------------------------------------------------------------------
// S1: per-(row, 32-col-group) maxima (1-term f16) with IN-REGISTER per-row
// sorted top-12 of this chunk's 48 group maxima. 2-tile phases: 48 barriers,
// 3 x 16KB buffers, counted vmcnt(4), 2-phase-deep prefetch.
// Grid = 8 chunks x 96 rowblocks = 768 blocks (3/CU). 128 rows/block.
// ---------------------------------------------------------------------------
__global__ __launch_bounds__(256, 2) void s1_gmax(
    const _Float16* __restrict__ ehh, const _Float16* __restrict__ eth,
    float* __restrict__ tau12)
{
    __shared__ _Float16 abuf[3][8192];          // 3 x 16KB phase buffers
    const int tid = threadIdx.x, lane = tid & 63, wave = tid >> 6;
    const int chunk = blockIdx.x & (NCH-1);     // == XCD id (L2 affinity)
    const int rblk = blockIdx.x >> 3;           // 0..95
    const int rg0 = rblk * 8 + wave * 2;

    f16x8 bh[2][8];
    #pragma unroll
    for (int rs = 0; rs < 2; ++rs) {
        const _Float16* p = ehh + (size_t)(rg0 + rs)*4096 + lane*8;
        #pragma unroll
        for (int s = 0; s < 8; ++s) bh[rs][s] = *(const f16x8*)(p + s*512);
    }
    #pragma unroll
    for (int rs = 0; rs < 2; ++rs)
        #pragma unroll
        for (int s = 0; s < 8; ++s)
            asm volatile("" : "+v"(bh[rs][s]));

    float tv0[TK], tv1[TK];
    #pragma unroll
    for (int j = 0; j < TK; ++j) { tv0[j] = NEG_BIG; tv1[j] = NEG_BIG; }

    const _Float16* gsrc = eth + (size_t)chunk * CTILES * 4096;
    // prologue: stage phases 0,1 (4 gloads/wave each; unit u: tile u>>3, k u&7)
    #pragma unroll
    for (int ph = 0; ph < 2; ++ph) {
        #pragma unroll
        for (int i = 0; i < 4; ++i) {
            const int u = wave*4 + i;
            gload_lds16(gsrc + (size_t)(ph*2 + (u>>3))*4096 + (u&7)*512 + lane*8,
                        &abuf[ph][u*512]);
        }
    }
    asm volatile("s_waitcnt vmcnt(4) lgkmcnt(0)" ::: "memory");
    __builtin_amdgcn_s_barrier();
    asm volatile("" ::: "memory");

    int cur = 0;
    for (int p = 0; p < NPH; ++p) {
        int nx = cur + 2; if (nx >= 3) nx -= 3;
        if (p + 2 < NPH) {
            #pragma unroll
            for (int i = 0; i < 4; ++i) {
                const int u = wave*4 + i;
                gload_lds16(gsrc + (size_t)((p+2)*2 + (u>>3))*4096 + (u&7)*512 + lane*8,
                            &abuf[nx][u*512]);
            }
        }
        float gm0 = NEG_BIG, gm1 = NEG_BIG;
        #pragma unroll
        for (int tt = 0; tt < 2; ++tt) {
            f32x4 aE[2], aO[2];
            #pragma unroll
            for (int rs = 0; rs < 2; ++rs) {
                aE[rs] = (f32x4){0.f,0.f,0.f,0.f};
                aO[rs] = (f32x4){0.f,0.f,0.f,0.f};
            }
            #pragma unroll
            for (int s = 0; s < 8; ++s) {
                f16x8 ah = *(const f16x8*)&abuf[cur][tt*4096 + s*512 + lane*8];
                if (s & 1) {
                    aO[0] = MFMA16(ah, bh[0][s], aO[0]);
                    aO[1] = MFMA16(ah, bh[1][s], aO[1]);
                } else {
                    aE[0] = MFMA16(ah, bh[0][s], aE[0]);
                    aE[1] = MFMA16(ah, bh[1][s], aE[1]);
                }
            }
            f32x4 a0 = aE[0] + aO[0];
            f32x4 a1 = aE[1] + aO[1];
            gm0 = fmaxf(gm0, fmaxf(fmaxf(a0[0],a0[1]), fmaxf(a0[2],a0[3])));
            gm1 = fmaxf(gm1, fmaxf(fmaxf(a1[0],a1[1]), fmaxf(a1[2],a1[3])));
        }
        // one cross-lane reduce per group (group == phase == 32 cols)
        gm0 = fmaxf(gm0, __shfl_xor(gm0, 16)); gm0 = fmaxf(gm0, __shfl_xor(gm0, 32));
        gm1 = fmaxf(gm1, __shfl_xor(gm1, 16)); gm1 = fmaxf(gm1, __shfl_xor(gm1, 32));
        // branchless in-register sorted insert (all lanes redundantly)
        #pragma unroll
        for (int j = TK-1; j >= 1; --j)
            tv0[j] = __builtin_amdgcn_fmed3f(gm0, tv0[j], tv0[j-1]);
        tv0[0] = fmaxf(gm0, tv0[0]);
        #pragma unroll
        for (int j = TK-1; j >= 1; --j)
            tv1[j] = __builtin_amdgcn_fmed3f(gm1, tv1[j], tv1[j-1]);
        tv1[0] = fmaxf(gm1, tv1[0]);

        if (p + 2 < NPH) { asm volatile("s_waitcnt vmcnt(4)" ::: "memory"); }
        else             { asm volatile("s_waitcnt vmcnt(0)" ::: "memory"); }
        __builtin_amdgcn_s_barrier();
        asm volatile("" ::: "memory");
        cur = cur + 1; if (cur >= 3) cur = 0;
    }

    if (lane < 16) {
        const int row0 = rg0 * 16 + lane;
        float* op0 = tau12 + ((size_t)chunk*NROW + row0)*TK;
        float* op1 = tau12 + ((size_t)chunk*NROW + row0 + 16)*TK;
        #pragma unroll
        for (int j = 0; j < TK; ++j) { op0[j] = tv0[j]; op1[j] = tv1[j]; }
    }
}

// ---------------------------------------------------------------------------
// B1: tau[row] = 12th-largest of the union of 8 per-chunk top-12 lists, - margin.
// ---------------------------------------------------------------------------
__global__ __launch_bounds__(256) void b1_tau(
    const float* __restrict__ tau12, float* __restrict__ tau)
{
    const int row = blockIdx.x * 256 + threadIdx.x;
    float tv[TK];
    #pragma unroll
    for (int j = 0; j < TK; ++j) tv[j] = NEG_BIG;
    #pragma unroll 1
    for (int c = 0; c < NCH; ++c) {
        const float* p = tau12 + ((size_t)c*NROW + row)*TK;
        float4 q0 = *(const float4*)p;
        float4 q1 = *(const float4*)(p + 4);
        float4 q2 = *(const float4*)(p + 8);
        float vv[TK] = {q0.x,q0.y,q0.z,q0.w, q1.x,q1.y,q1.z,q1.w, q2.x,q2.y,q2.z,q2.w};
        #pragma unroll
        for (int i = 0; i < TK; ++i) {
            float v = vv[i];
            #pragma unroll
            for (int j = TK-1; j >= 1; --j)
                tv[j] = __builtin_amdgcn_fmed3f(v, tv[j], tv[j-1]);
            tv[0] = fmaxf(v, tv[0]);
        }
    }
    tau[row] = tv[TK-1] - 0.02f;
}

// ---------------------------------------------------------------------------
// S2: 1-term scores; collect columns >= tau[row] into LDS, flush once.
// Same 2-tile-phase pipeline as S1.
// ---------------------------------------------------------------------------
#define S2CAP 1024
__global__ __launch_bounds__(256, 2) void s2_collect(
    const _Float16* __restrict__ ehh, const _Float16* __restrict__ eth,
    const float* __restrict__ tau, unsigned int* __restrict__ cnt,
    int* __restrict__ cand)
{
    __shared__ _Float16 abuf[3][8192];
    __shared__ int cmeta[S2CAP];
    __shared__ unsigned int lcnt;
    const int tid = threadIdx.x, lane = tid & 63, wave = tid >> 6;
    const int chunk = blockIdx.x & (NCH-1);
    const int rblk = blockIdx.x >> 3;
    const int rg0 = rblk * 8 + wave * 2;
    if (tid == 0) lcnt = 0;

    f16x8 bh[2][8];
    #pragma unroll
    for (int rs = 0; rs < 2; ++rs) {
        const _Float16* p = ehh + (size_t)(rg0 + rs)*4096 + lane*8;
        #pragma unroll
        for (int s = 0; s < 8; ++s) bh[rs][s] = *(const f16x8*)(p + s*512);
    }
    #pragma unroll
    for (int rs = 0; rs < 2; ++rs)
        #pragma unroll
        for (int s = 0; s < 8; ++s)
            asm volatile("" : "+v"(bh[rs][s]));

    const float tau0 = tau[rblk*128 + wave*32 + (lane & 15)];
    const float tau1 = tau[rblk*128 + wave*32 + 16 + (lane & 15)];

    const _Float16* gsrc = eth + (size_t)chunk * CTILES * 4096;
    #pragma unroll
    for (int ph = 0; ph < 2; ++ph) {
        #pragma unroll
        for (int i = 0; i < 4; ++i) {
            const int u = wave*4 + i;
            gload_lds16(gsrc + (size_t)(ph*2 + (u>>3))*4096 + (u&7)*512 + lane*8,
                        &abuf[ph][u*512]);
        }
    }
    asm volatile("s_waitcnt vmcnt(4) lgkmcnt(0)" ::: "memory");
    __builtin_amdgcn_s_barrier();
    asm volatile("" ::: "memory");

    int cur = 0;
    for (int p = 0; p < NPH; ++p) {
        int nx = cur + 2; if (nx >= 3) nx -= 3;
        if (p + 2 < NPH) {
            #pragma unroll
            for (int i = 0; i < 4; ++i) {
                const int u = wave*4 + i;
                gload_lds16(gsrc + (size_t)((p+2)*2 + (u>>3))*4096 + (u&7)*512 + lane*8,
                            &abuf[nx][u*512]);
            }
        }
        #pragma unroll
        for (int tt = 0; tt < 2; ++tt) {
            f32x4 aE[2], aO[2];
            #pragma unroll
            for (int rs = 0; rs < 2; ++rs) {
                aE[rs] = (f32x4){0.f,0.f,0.f,0.f};
                aO[rs] = (f32x4){0.f,0.f,0.f,0.f};
            }
            #pragma unroll
            for (int s = 0; s < 8; ++s) {
                f16x8 ah = *(const f16x8*)&abuf[cur][tt*4096 + s*512 + lane*8];
                if (s & 1) {
                    aO[0] = MFMA16(ah, bh[0][s], aO[0]);
                    aO[1] = MFMA16(ah, bh[1][s], aO[1]);
                } else {
                    aE[0] = MFMA16(ah, bh[0][s], aE[0]);
                    aE[1] = MFMA16(ah, bh[1][s], aE[1]);
                }
            }
            const int cb = (chunk*CTILES + p*2 + tt)*16 + 4*(lane >> 4);
            f32x4 a0 = aE[0] + aO[0];
            f32x4 a1 = aE[1] + aO[1];
            float m0 = fmaxf(fmaxf(a0[0],a0[1]), fmaxf(a0[2],a0[3]));
            float m1 = fmaxf(fmaxf(a1[0],a1[1]), fmaxf(a1[2],a1[3]));
            if (__any(m0 >= tau0 || m1 >= tau1)) {
                const int lrow = wave*32 + (lane & 15);
                #pragma unroll
                for (int e = 0; e < 4; ++e) {
                    if (a0[e] >= tau0) {
                        unsigned q = atomicAdd(&lcnt, 1u);
                        if (q < S2CAP) cmeta[q] = (cb + e) | (lrow << 16);
                    }
                    if (a1[e] >= tau1) {
                        unsigned q = atomicAdd(&lcnt, 1u);
                        if (q < S2CAP) cmeta[q] = (cb + e) | ((lrow + 16) << 16);
                    }
                }
            }
        }
        if (p + 2 < NPH) { asm volatile("s_waitcnt vmcnt(4)" ::: "memory"); }
        else             { asm volatile("s_waitcnt vmcnt(0)" ::: "memory"); }
        __builtin_amdgcn_s_barrier();
        asm volatile("" ::: "memory");
        cur = cur + 1; if (cur >= 3) cur = 0;
    }
    asm volatile("s_waitcnt lgkmcnt(0)" ::: "memory");
    __builtin_amdgcn_s_barrier();
    asm volatile("" ::: "memory");
    const int row0 = rblk * 128;
    const unsigned n = (lcnt < (unsigned)S2CAP) ? lcnt : (unsigned)S2CAP;
    for (unsigned i = tid; i < n; i += 256) {
        const int m = cmeta[i];
        const int row = row0 + (m >> 16);
        unsigned q = atomicAdd(&cnt[row], 1u);
        if (q < 64) cand[(size_t)row*64 + q] = m & 0xffff;
    }
}

// ---------------------------------------------------------------------------
// S3: exact f32 rescoring of candidates, top-12 (val desc, col asc),
// softmax / gather / tanh-gate / ka-softmax / e_Nh. One wave per row.
// ---------------------------------------------------------------------------
__global__ __launch_bounds__(256) void s3_tail(
    const float* __restrict__ e_h, const float* __restrict__ e_t,
    const unsigned int* __restrict__ cnt, const int* __restrict__ cand,
    float* __restrict__ e_Nh)
{
    const int lane = threadIdx.x & 63;
    const int wave = threadIdx.x >> 6;
    const int row  = blockIdx.x * 4 + wave;

    const unsigned cn = min(cnt[row], 64u);
    const bool act = lane < (int)cn;
    int colc = act ? cand[(size_t)row*64 + lane] : 0x7fffffff;

    const float* ehr = e_h + (size_t)row * 256;
    const float* etr = e_t + (size_t)(act ? colc : 0) * 256;
    float s = 0.f;
    for (int k = 0; k < 64; ++k) {
        float4 a = *(const float4*)(ehr + k*4);
        float4 b = *(const float4*)(etr + k*4);
        s += a.x*b.x + a.y*b.y + a.z*b.z + a.w*b.w;
    }
    s *= 0.0625f;
    if (!act) s = NEG_BIG;

    float tvv[TK]; int ti[TK];
    float v = s; int c = colc;
    #pragma unroll
    for (int o = 0; o < TK; ++o) {
        float bv = v; int bc = c;
        #pragma unroll
        for (int off = 32; off; off >>= 1) {
            float ov = __shfl_xor(bv, off);
            int   oc = __shfl_xor(bc, off);
            bool take = (ov > bv) || (ov == bv && oc < bc);
            bv = take ? ov : bv;
            bc = take ? oc : bc;
        }
        tvv[o] = bv; ti[o] = bc;
        if (c == bc) v = NEG_BIG;
    }

    float p[TK]; float Z = 0.f;
    #pragma unroll
    for (int j = 0; j < TK; ++j) { p[j] = expf(tvv[j] - tvv[0]); Z += p[j]; }
    const float invZ = 1.f / Z;
    #pragma unroll
    for (int j = 0; j < TK; ++j) p[j] *= invZ;

    float4 eh = *(const float4*)(ehr + lane * 4);

    float4 nb[TK]; float kw[TK];
    #pragma unroll
    for (int k = 0; k < TK; ++k) {
        float4 n = *(const float4*)(e_t + (size_t)ti[k] * 256 + lane * 4);
        nb[k] = n;
        const float pk = p[k], qk = 1.f - p[k];
        float4 gt;
        gt.x = tanhf(eh.x + (pk * n.x + qk * eh.x));
        gt.y = tanhf(eh.y + (pk * n.y + qk * eh.y));
        gt.z = tanhf(eh.z + (pk * n.z + qk * eh.z));
        gt.w = tanhf(eh.w + (pk * n.w + qk * eh.w));
        float d = n.x*gt.x + n.y*gt.y + n.z*gt.z + n.w*gt.w;
        #pragma unroll
        for (int off = 32; off; off >>= 1) d += __shfl_xor(d, off);
        kw[k] = d;
    }

    float km = kw[0];
    #pragma unroll
    for (int k = 1; k < TK; ++k) km = fmaxf(km, kw[k]);
    float kz = 0.f; float kp[TK];
    #pragma unroll
    for (int k = 0; k < TK; ++k) { kp[k] = expf(kw[k] - km); kz += kp[k]; }
    const float invKZ = 1.f / kz;

    float4 acc = make_float4(0.f, 0.f, 0.f, 0.f);
    #pragma unroll
    for (int k = 0; k < TK; ++k) {
        acc.x += kp[k] * nb[k].x;
        acc.y += kp[k] * nb[k].y;
        acc.z += kp[k] * nb[k].z;
        acc.w += kp[k] * nb[k].w;
    }
    acc.x *= invKZ; acc.y *= invKZ; acc.z *= invKZ; acc.w *= invKZ;
    *(float4*)(e_Nh + (size_t)row * 256 + lane * 4) = acc;
}

// ---------------------------------------------------------------------------
extern "C" void kernel_launch(void* const* d_in, const int* in_sizes, int n_in,
                              void* d_out, int out_size, void* d_ws, size_t ws_size,
                              hipStream_t stream)
{
    (void)in_sizes; (void)n_in; (void)out_size; (void)ws_size;
    const float* x     = (const float*)d_in[0];
    const float* wsi_w = (const float*)d_in[1];
    const float* wsi_b = (const float*)d_in[2];
    const float* wh_w  = (const float*)d_in[3];
    const float* wh_b  = (const float*)d_in[4];
    const float* wt_w  = (const float*)d_in[5];
    const float* wt_b  = (const float*)d_in[6];
    const float* w1_w  = (const float*)d_in[7];
    const float* w1_b  = (const float*)d_in[8];
    const float* w2_w  = (const float*)d_in[9];
    const float* w2_b  = (const float*)d_in[10];
    float* out = (float*)d_out;
    float* ws  = (float*)d_ws;

    const int M = NROW;
    const size_t ND = (size_t)M * 256;            // 3,145,728

    float* h    = ws;                             // reused as e_Nh
    float* e_h  = ws + ND;
    float* e_t  = ws + 2*ND;
    _Float16* ehh = (_Float16*)(ws + 3*ND);       // ND halfs
    _Float16* eth = (_Float16*)(ws + 3*ND + ND/2);
    size_t o = 4*ND;
    float* tau12 = ws + o;                        o += (size_t)NCH*NROW*TK;
    float* tau = ws + o;                          o += NROW;
    unsigned int* cnt = (unsigned int*)(ws + o);  o += NROW;
    int* cand = (int*)(ws + o);                   o += (size_t)NROW*64;
    _Float16* hp = (_Float16*)(ws + o);
    _Float16* wsiH = hp;                 // 1024*256 halfs
    _Float16* wsiL = hp + 262144;
    _Float16* w4base = hp + 524288;      // wh{H,L}, wt{H,L}, w1{H,L}, w2{H,L}
    _Float16* whH  = w4base;
    _Float16* whL  = w4base + 65536;
    _Float16* wtH  = w4base + 2*65536;
    _Float16* wtL  = w4base + 3*65536;
    _Float16* w1H  = w4base + 4*65536;
    _Float16* w1L  = w4base + 5*65536;
    _Float16* w2H  = w4base + 6*65536;
    _Float16* w2L  = w4base + 7*65536;
    float* e_Nh = h;

    // pack weights into fragment layout
    wpack<<<128, 256, 0, stream>>>(wsi_w, wsiH, wsiL, 256, 32);
    wpack4<<<dim3(32, 4), 256, 0, stream>>>(wh_w, wt_w, w1_w, w2_w, w4base);

    // K1: h = relu(x @ wsi + b)
    gemm_mfma<true><<<dim3(4, M/64), 256, 0, stream>>>(
        x, wsiH, wsiL, wsi_b, h, 1024);
    // K2 fused: e_h, e_t + packed ehh (x SCALE), eth in epilogue
    gemm_dual<0><<<dim3(4, M/64), 256, 0, stream>>>(
        h, nullptr, whH, whL, wtH, wtL, wh_b, wt_b, e_h, e_t, ehh, eth);
    // S1 / B1 / S2 / S3
    s1_gmax<<<NCH*96, 256, 0, stream>>>(ehh, eth, tau12);
    b1_tau<<<M/256, 256, 0, stream>>>(tau12, tau);
    hipMemsetAsync(cnt, 0, (size_t)M*sizeof(unsigned int), stream);
    s2_collect<<<NCH*96, 256, 0, stream>>>(ehh, eth, tau, cnt, cand);
    s3_tail<<<M/4, 256, 0, stream>>>(e_h, e_t, cnt, cand, e_Nh);
    // K5 fused: out = relu((e_h+e_Nh)@w1+b1) + relu((e_h*e_Nh)@w2+b2)
    gemm_dual<1><<<dim3(4, M/64), 256, 0, stream>>>(
        e_h, e_Nh, w1H, w1L, w2H, w2L, w1_b, w2_b, out, nullptr, nullptr, nullptr);
}